// Round 11
// baseline (1106.936 us; speedup 1.0000x reference)
//
#include <hip/hip_runtime.h>

// ---------------- problem constants ----------------
#define NB    2
#define QLEN  512
#define HIDD  5120
#define QLORA 1536
#define NHEAD 128
#define QHD   192
#define VHD   128
#define KVTOT 1024

typedef float          f32x4   __attribute__((ext_vector_type(4)));
typedef __bf16         bf16x8  __attribute__((ext_vector_type(8)));
typedef unsigned short u16x8   __attribute__((ext_vector_type(8)));
typedef unsigned short u16x4   __attribute__((ext_vector_type(4)));

static __device__ __forceinline__ unsigned short f2bf(float f) {
  union { float f; unsigned u; } v; v.f = f;
  return (unsigned short)((v.u + 0x7fffu + ((v.u >> 16) & 1u)) >> 16);
}

static __device__ __forceinline__ void g2l16(const void* g, void* l) {
  __builtin_amdgcn_global_load_lds(
      (const __attribute__((address_space(1))) void*)g,
      (__attribute__((address_space(3))) void*)l, 16, 0, 0);
}

// ---------------- zero the 64 pad rows of stacked wkva (640 KB) ----------------
__global__ __launch_bounds__(256) void zero_pad_k(unsigned short* __restrict__ dst) {
  int i = blockIdx.x * 256 + threadIdx.x;
  u16x8 z = {0, 0, 0, 0, 0, 0, 0, 0};
  *(u16x8*)(dst + (long)i * 8) = z;
}

// ---------------- merged f32 -> bf16 converts (5 segments) ----------------
struct CvtArgs {
  const float* src[5];
  unsigned short* dst[5];
  int off[6];
};

__global__ __launch_bounds__(256) void cvt_all_k(CvtArgs a) {
  int b = blockIdx.x, s = 0;
  #pragma unroll
  for (int k = 0; k < 4; ++k) if (b >= a.off[k + 1]) s = k + 1;
  long lb = b - a.off[s];
  const float* in = a.src[s];
  unsigned short* out = a.dst[s];
  long base = lb * 1024 + threadIdx.x;
  #pragma unroll
  for (int k = 0; k < 4; ++k) {
    long i = base + k * 256;
    f32x4 v = *(const f32x4*)(in + i * 4);
    u16x4 o;
    o[0] = f2bf(v[0]); o[1] = f2bf(v[1]); o[2] = f2bf(v[2]); o[3] = f2bf(v[3]);
    *(u16x4*)(out + i * 4) = o;
  }
}

// ---------------- mask zero-flags: 1 flag per (b, 128-qtile, 64-ktile) ----------------
__global__ __launch_bounds__(256) void flags_k(const float* __restrict__ mask,
                                               int* __restrict__ flags) {
  int id = blockIdx.x;
  int b = id >> 6, qt = (id >> 4) & 3, kt = id & 15;
  const float* base = mask + (long)b * 524288 + (long)qt * 128 * 1024 + kt * 64;
  int t = threadIdx.x, w = t >> 6;
  unsigned acc = 0;
  #pragma unroll
  for (int i = 0; i < 32; ++i) {
    int e = i * 256 + t;
    int r = e >> 6, c = e & 63;
    union { float f; unsigned u; } v; v.f = base[(long)r * 1024 + c];
    acc |= v.u;
  }
  int any = __any(acc != 0);
  __shared__ int sf[4];
  if ((t & 63) == 0) sf[w] = any;
  __syncthreads();
  if (t == 0) flags[id] = sf[0] | sf[1] | sf[2] | sf[3];
}

// ---------------- fused q_a + ckv GEMM, split-K(2): 128x64 tile, 4 waves ----------------
// 1D grid 576 (pz-space padded 68->72 = 8x9 for BIJECTIVE XCD remap; pz>=68 exits).
__global__ __launch_bounds__(256, 4) void gemm_qa_ckv(const unsigned short* __restrict__ A,
                                                      const unsigned short* __restrict__ Bm,
                                                      float* __restrict__ part) {
  __shared__ __align__(16) unsigned short sA[128 * 64];
  __shared__ __align__(16) unsigned short sB[64 * 64];
  const int t = threadIdx.x, w = t >> 6, l = t & 63;
  const int l15 = l & 15, lh = l >> 4;
  const int swz7 = l15 & 7;
  const int id = blockIdx.x;
  const int xcd = id & 7, slot = id >> 3;
  const int pz = xcd + 8 * (slot >> 3);
  const int mb = slot & 7;
  if (pz >= 68) return;
  const int z = (pz >= 34) ? 1 : 0;
  const int nb = pz - z * 34;
  const unsigned short* Ab = A + (long)mb * 128 * HIDD;
  const unsigned short* Bb = Bm + (long)nb * 64 * HIDD;
  f32x4 acc[2][4];
  #pragma unroll
  for (int i = 0; i < 2; ++i)
    #pragma unroll
    for (int j = 0; j < 4; ++j)
      #pragma unroll
      for (int r = 0; r < 4; ++r) acc[i][j][r] = 0.f;

  const int k0 = z * 2560;
  for (int kt = k0; kt < k0 + 2560; kt += 64) {
    #pragma unroll
    for (int i2 = 0; i2 < 4; ++i2) {
      int n = i2 * 256 + t, r = n >> 3, c = (n & 7) ^ (r & 7);
      g2l16(Ab + (long)r * HIDD + kt + c * 8, (char*)sA + (i2 * 256 + w * 64) * 16);
    }
    #pragma unroll
    for (int i2 = 0; i2 < 2; ++i2) {
      int n = i2 * 256 + t, r = n >> 3, c = (n & 7) ^ (r & 7);
      g2l16(Bb + (long)r * HIDD + kt + c * 8, (char*)sB + (i2 * 256 + w * 64) * 16);
    }
    __syncthreads();
    #pragma unroll
    for (int ks = 0; ks < 2; ++ks) {
      bf16x8 af[2], bfr[4];
      #pragma unroll
      for (int i = 0; i < 2; ++i)
        af[i] = *(const bf16x8*)(sA + (w * 32 + i * 16 + l15) * 64 + ((ks * 4 + lh) ^ swz7) * 8);
      #pragma unroll
      for (int j = 0; j < 4; ++j)
        bfr[j] = *(const bf16x8*)(sB + (j * 16 + l15) * 64 + ((ks * 4 + lh) ^ swz7) * 8);
      #pragma unroll
      for (int i = 0; i < 2; ++i)
        #pragma unroll
        for (int j = 0; j < 4; ++j)
          acc[i][j] = __builtin_amdgcn_mfma_f32_16x16x32_bf16(af[i], bfr[j], acc[i][j], 0, 0, 0);
    }
    __syncthreads();
  }
  float* po = part + (long)z * 1024 * 2176;
  const int colbase = nb * 64;
  #pragma unroll
  for (int i = 0; i < 2; ++i)
    #pragma unroll
    for (int j = 0; j < 4; ++j) {
      const int col = colbase + j * 16 + l15;
      #pragma unroll
      for (int r4 = 0; r4 < 4; ++r4) {
        const long row = (long)mb * 128 + w * 32 + i * 16 + lh * 4 + r4;
        po[row * 2176 + col] = acc[i][j][r4];
      }
    }
}

// ---------------- fused rmsnorm(q_a) + rmsnorm(ckv) + k_pe broadcast (2 partials) ------
__global__ __launch_bounds__(256) void post_a_k(const float* __restrict__ part,
                                                const float* __restrict__ gq,
                                                const float* __restrict__ gkv,
                                                unsigned short* __restrict__ qan,
                                                unsigned short* __restrict__ ckvn,
                                                float* __restrict__ kout,
                                                unsigned short* __restrict__ kb) {
  const long ZS = 1024L * 2176;
  int bid = blockIdx.x, t = threadIdx.x;
  if (bid >= 2048) {  // k_pe broadcast
    int row = bid - 2048;
    int j = t & 63, h0 = t >> 6;
    const float* p = part + (long)row * 2176 + 2048 + j;
    float v = p[0] + p[ZS];
    unsigned short vb = f2bf(v);
    long b_ = row >> 9, qi = row & 511;
    for (int h = h0; h < NHEAD; h += 4) {
      long idx = ((b_ * NHEAD + h) * KVTOT + 512 + qi) * QHD + 128 + j;
      kout[idx] = v;
      kb[idx] = vb;
    }
    return;
  }
  bool isQ = bid < 1024;
  int row = isQ ? bid : bid - 1024;
  int cols = isQ ? 1536 : 512;
  const float* g = isQ ? gq : gkv;
  unsigned short* out = isQ ? (qan + (long)row * 1536) : (ckvn + (long)row * 512);
  const float* x = part + (long)row * 2176 + (isQ ? 0 : 1536);
  int w = t >> 6, l = t & 63;
  float xv[6];
  int nc = cols >> 8;
  float ss = 0.f;
  for (int i = 0; i < nc; ++i) {
    int c = t + i * 256;
    float v = x[c] + x[c + ZS];
    xv[i] = v; ss += v * v;
  }
  #pragma unroll
  for (int m = 32; m >= 1; m >>= 1) ss += __shfl_xor(ss, m);
  __shared__ float red[4];
  if (l == 0) red[w] = ss;
  __syncthreads();
  float tot = red[0] + red[1] + red[2] + red[3];
  float rs = rsqrtf(tot / (float)cols + 1e-6f);
  for (int i = 0; i < nc; ++i) {
    int c = t + i * 256;
    out[c] = f2bf(g[c] * xv[i] * rs);
  }
}

// ---------------- merged Q-GEMM + KV-GEMM: 128x128 tile, BK=64, 4 waves ----------------
__global__ __launch_bounds__(256, 4) void gemm_bt2(const unsigned short* __restrict__ Aq,
                                                   const unsigned short* __restrict__ Bq,
                                                   const unsigned short* __restrict__ Akv,
                                                   const unsigned short* __restrict__ Bkv,
                                                   unsigned short* __restrict__ qout,
                                                   float* __restrict__ kout,
                                                   float* __restrict__ vout,
                                                   unsigned short* __restrict__ kb,
                                                   unsigned short* __restrict__ vt) {
  __shared__ __align__(16) unsigned short sA[128 * 64];
  __shared__ __align__(16) unsigned short sB[128 * 64];
  const int t = threadIdx.x, w = t >> 6, l = t & 63;
  const int l15 = l & 15, lh = l >> 4;
  const int swz7 = l15 & 7;
  const int wm = w >> 1, wn = w & 1;
  const int id = blockIdx.x;
  const int xcd = id & 7, slot = id >> 3;
  const int y = xcd + 8 * (slot >> 3);
  const int mb = slot & 7;
  const bool isQ = y < 192;
  const int nb = isQ ? y : y - 192;
  const int K = isQ ? QLORA : 512;
  const unsigned short* Ab = (isQ ? Aq : Akv) + (long)mb * 128 * K;
  const unsigned short* Bb = (isQ ? Bq : Bkv) + (long)nb * 128 * K;
  f32x4 acc[4][4];
  #pragma unroll
  for (int i = 0; i < 4; ++i)
    #pragma unroll
    for (int j = 0; j < 4; ++j)
      #pragma unroll
      for (int r = 0; r < 4; ++r) acc[i][j][r] = 0.f;

  const int srow = l >> 3;
  const int scol = ((l & 7) ^ srow) * 8;

  for (int kt = 0; kt < K; kt += 64) {
    #pragma unroll
    for (int i = 0; i < 4; ++i) {
      const int chunk = i * 4 + w;
      const int r = chunk * 8 + srow;
      g2l16(Ab + (long)r * K + kt + scol, (char*)sA + chunk * 1024);
      g2l16(Bb + (long)r * K + kt + scol, (char*)sB + chunk * 1024);
    }
    __syncthreads();
    #pragma unroll
    for (int ks = 0; ks < 2; ++ks) {
      bf16x8 af[4], bfr[4];
      #pragma unroll
      for (int i = 0; i < 4; ++i)
        af[i] = *(const bf16x8*)(sA + (wm * 64 + i * 16 + l15) * 64 + ((ks * 4 + lh) ^ swz7) * 8);
      #pragma unroll
      for (int j = 0; j < 4; ++j)
        bfr[j] = *(const bf16x8*)(sB + (wn * 64 + j * 16 + l15) * 64 + ((ks * 4 + lh) ^ swz7) * 8);
      #pragma unroll
      for (int i = 0; i < 4; ++i)
        #pragma unroll
        for (int j = 0; j < 4; ++j)
          acc[i][j] = __builtin_amdgcn_mfma_f32_16x16x32_bf16(af[i], bfr[j], acc[i][j], 0, 0, 0);
    }
    __syncthreads();
  }

  const long rowbase = (long)mb * 128 + wm * 64;
  const long b_ = rowbase >> 9;
  const int colbase = nb * 128 + wn * 64;
  #pragma unroll
  for (int i = 0; i < 4; ++i) {
    const long qi0 = (rowbase + i * 16 + lh * 4) & 511;
    #pragma unroll
    for (int j = 0; j < 4; ++j) {
      const int col = colbase + j * 16 + l15;
      if (isQ) {
        const int h = col / QHD, d = col - h * QHD;
        unsigned short* qp = qout + ((b_ * NHEAD + h) * QLEN + qi0) * QHD + d;
        #pragma unroll
        for (int r4 = 0; r4 < 4; ++r4) qp[(long)r4 * QHD] = f2bf(acc[i][j][r4]);
      } else {
        const int h = col >> 8, d = col & 255;
        if (d < 128) {
          const long idx = ((b_ * NHEAD + h) * KVTOT + 512 + qi0) * QHD + d;
          #pragma unroll
          for (int r4 = 0; r4 < 4; ++r4) {
            kout[idx + (long)r4 * QHD] = acc[i][j][r4];
            kb[idx + (long)r4 * QHD] = f2bf(acc[i][j][r4]);
          }
        } else {
          const int dv = d - 128;
          float* vp = vout + ((b_ * NHEAD + h) * KVTOT + 512 + qi0) * VHD + dv;
          u16x4 tv;
          #pragma unroll
          for (int r4 = 0; r4 < 4; ++r4) {
            vp[(long)r4 * VHD] = acc[i][j][r4];
            tv[r4] = f2bf(acc[i][j][r4]);
          }
          *(u16x4*)(vt + ((b_ * NHEAD + h) * VHD + dv) * KVTOT + 512 + qi0) = tv;
        }
      }
    }
  }
}

// ---------------- past key copy: f32 out + bf16 ws ----------------
__global__ __launch_bounds__(256) void copy_key_past_k(const float* __restrict__ pk,
                                                       float* __restrict__ kout,
                                                       unsigned short* __restrict__ kb) {
  long i4 = (long)blockIdx.x * 256 + threadIdx.x;
  f32x4 v = *(const f32x4*)(pk + i4 * 4);
  long e = i4 * 4;
  long bh = e / 98304;
  long rem = e - bh * 98304;
  long oidx = bh * 196608 + rem;
  *(f32x4*)(kout + oidx) = v;
  u16x4 b;
  b[0] = f2bf(v[0]); b[1] = f2bf(v[1]); b[2] = f2bf(v[2]); b[3] = f2bf(v[3]);
  *(u16x4*)(kb + oidx) = b;
}

// ---------------- V past rows only: copy pv -> out_val + transpose -> Vt bf16 ----------
__global__ __launch_bounds__(256) void vfix_k(const float* __restrict__ pv,
                                              float* __restrict__ outv,
                                              unsigned short* __restrict__ vt) {
  __shared__ __align__(16) unsigned short sT[128 * 72];
  int bh = blockIdx.x >> 3, kt = blockIdx.x & 7;
  int t = threadIdx.x;
  const float* src = pv + ((long)bh * 512 + kt * 64) * VHD;
  float* dstv = outv + ((long)bh * KVTOT + kt * 64) * VHD;
  #pragma unroll
  for (int i = 0; i < 8; ++i) {
    int id = t + i * 256;
    int r = id >> 5, c4 = (id & 31) * 4;
    f32x4 v = *(const f32x4*)(src + (long)r * VHD + c4);
    *(f32x4*)(dstv + (long)r * VHD + c4) = v;
    #pragma unroll
    for (int jj = 0; jj < 4; ++jj) sT[(c4 + jj) * 72 + r] = f2bf(v[jj]);
  }
  __syncthreads();
  #pragma unroll
  for (int i = 0; i < 4; ++i) {
    int id = t + i * 256;
    int d = id >> 3, c = id & 7;
    u16x8 v = *(const u16x8*)(sT + d * 72 + c * 8);
    *(u16x8*)(vt + ((long)bh * VHD + d) * KVTOT + kt * 64 + c * 8) = v;
  }
}

// ---------------- attention staging helpers (XOR-swizzled source, linear LDS dest) ----
static __device__ __forceinline__ void stage_k_tile(const unsigned short* __restrict__ src,
                                                    char* dstbase, int t) {
  const int w = t >> 6;
  #pragma unroll
  for (int i2 = 0; i2 < 6; ++i2) {
    int n = i2 * 256 + t;
    int r = n / 24, cp = n - r * 24;
    int c = cp ^ (r & 7);
    g2l16(src + (long)r * QHD + c * 8, dstbase + (i2 * 256 + w * 64) * 16);
  }
}

static __device__ __forceinline__ void stage_v_tile(const unsigned short* __restrict__ src,
                                                    char* dstbase, int t) {
  const int w = t >> 6;
  #pragma unroll
  for (int i2 = 0; i2 < 4; ++i2) {
    int n = i2 * 256 + t;
    int r = n >> 3, cp = n & 7;
    int c = cp ^ (r & 7);
    g2l16(src + (long)r * KVTOT + c * 8, dstbase + (i2 * 256 + w * 64) * 16);
  }
}

// ---------------- flash attention: 1 block = (b,h, 128-row q tile), 4 waves ------------
// HIGH-OCCUPANCY variant: single K buffer (sP aliased in after QK^T) + sV = 40 KB LDS
// -> 3-4 blocks/CU (vs 2). Staging latency exposed within a block (3 barriers/iter)
// but covered by cross-block TLP. V staged via global_load_lds (compiler can't sink it).
__global__ __launch_bounds__(256, 4) void attn_k(const unsigned short* __restrict__ Qw,
                                                 const unsigned short* __restrict__ Kb,
                                                 const unsigned short* __restrict__ Vt,
                                                 const float* __restrict__ mask,
                                                 const int* __restrict__ flags,
                                                 float* __restrict__ outp) {
  __shared__ __align__(16) unsigned short sK[64 * 192];   // 24 KB; doubles as sP after QK
  __shared__ __align__(16) unsigned short sV[128 * 64];   // 16 KB
  const int t = threadIdx.x, w = t >> 6, l = t & 63;
  const int l15 = l & 15, lh = l >> 4;
  const int raw = blockIdx.x;
  const int xcd = raw & 7, slot = raw >> 3;
  const int bh = xcd * 32 + (slot >> 2), qt = slot & 3;
  const long b_ = bh >> 7;
  const float SCALE = 0.051023330039633184f;
  const int swz = l15 & 7;

  bf16x8 qf[2][6];
  const unsigned short* Qb = Qw + ((long)bh * QLEN + qt * 128 + w * 32) * QHD;
  #pragma unroll
  for (int i = 0; i < 2; ++i)
    #pragma unroll
    for (int ks = 0; ks < 6; ++ks)
      qf[i][ks] = *(const bf16x8*)(Qb + (i * 16 + l15) * QHD + ks * 32 + lh * 8);

  f32x4 o[2][8];
  #pragma unroll
  for (int i = 0; i < 2; ++i)
    #pragma unroll
    for (int j = 0; j < 8; ++j)
      #pragma unroll
      for (int r = 0; r < 4; ++r) o[i][j][r] = 0.f;
  float m_[2][4], l_[2][4];  // l_ per-lane partial, reduced in epilogue
  #pragma unroll
  for (int i = 0; i < 2; ++i)
    #pragma unroll
    for (int r = 0; r < 4; ++r) { m_[i][r] = -1e30f; l_[i][r] = 0.f; }

  const int qrow0 = qt * 128 + w * 32;
  const unsigned short* Kbh = Kb + (long)bh * KVTOT * QHD;
  const unsigned short* Vbh = Vt + (long)bh * VHD * KVTOT;
  const float* mrow = mask + b_ * 524288 + (long)(qrow0 + lh * 4) * 1024 + l15;
  const int fbase = (int)b_ * 64 + qt * 16;

  for (int kt = 0; kt < 16; ++kt) {
    // stage this tile's K and V (async, drained at barrier B)
    stage_k_tile(Kbh + (long)kt * 64 * QHD, (char*)sK, t);
    stage_v_tile(Vbh + kt * 64, (char*)sV, t);
    const int flag = flags[fbase + kt];
    __syncthreads();  // B: staging drained (vmcnt(0))

    // S = Q K^T (swizzled sK reads)
    f32x4 s[2][4];
    #pragma unroll
    for (int i = 0; i < 2; ++i)
      #pragma unroll
      for (int j = 0; j < 4; ++j)
        #pragma unroll
        for (int r = 0; r < 4; ++r) s[i][j][r] = 0.f;
    __builtin_amdgcn_s_setprio(1);
    #pragma unroll
    for (int j = 0; j < 4; ++j) {
      #pragma unroll
      for (int ks = 0; ks < 6; ++ks) {
        bf16x8 kf = *(const bf16x8*)(sK + ((j * 16 + l15) * 24 + ((ks * 4 + lh) ^ swz)) * 8);
        s[0][j] = __builtin_amdgcn_mfma_f32_16x16x32_bf16(qf[0][ks], kf, s[0][j], 0, 0, 0);
        s[1][j] = __builtin_amdgcn_mfma_f32_16x16x32_bf16(qf[1][ks], kf, s[1][j], 0, 0, 0);
      }
    }
    __builtin_amdgcn_s_setprio(0);

    // online softmax
    unsigned short pk16[2][4][4];
    #pragma unroll
    for (int i = 0; i < 2; ++i) {
      #pragma unroll
      for (int rg = 0; rg < 4; ++rg) {
        float sc[4];
        if (flag) {
          #pragma unroll
          for (int j = 0; j < 4; ++j)
            sc[j] = s[i][j][rg] * SCALE + mrow[(long)(i * 16 + rg) * 1024 + kt * 64 + j * 16];
        } else {
          #pragma unroll
          for (int j = 0; j < 4; ++j) sc[j] = s[i][j][rg] * SCALE;
        }
        float mx = fmaxf(fmaxf(sc[0], sc[1]), fmaxf(sc[2], sc[3]));
        mx = fmaxf(mx, __shfl_xor(mx, 1));
        mx = fmaxf(mx, __shfl_xor(mx, 2));
        mx = fmaxf(mx, __shfl_xor(mx, 4));
        mx = fmaxf(mx, __shfl_xor(mx, 8));
        float mo = m_[i][rg];
        float mn = fmaxf(mo, mx);
        if (__any(mn > mo)) {
          float al = __expf(mo - mn);
          #pragma unroll
          for (int jj = 0; jj < 8; ++jj) o[i][jj][rg] *= al;
          l_[i][rg] *= al;
          m_[i][rg] = mn;
        }
        float ps = 0.f;
        #pragma unroll
        for (int j = 0; j < 4; ++j) {
          float p = __expf(sc[j] - m_[i][rg]);
          ps += p;
          pk16[i][rg][j] = f2bf(p);
        }
        l_[i][rg] += ps;
      }
    }
    __syncthreads();  // C: all QK^T reads of sK done -> safe to overwrite as sP

    // write P into sK space (stride 72, 18.4 KB < 24 KB)
    unsigned short* sPc = (unsigned short*)sK;
    #pragma unroll
    for (int i = 0; i < 2; ++i)
      #pragma unroll
      for (int rg = 0; rg < 4; ++rg) {
        const int prow = w * 32 + i * 16 + lh * 4 + rg;
        #pragma unroll
        for (int j = 0; j < 4; ++j)
          sPc[prow * 72 + j * 16 + l15] = pk16[i][rg][j];
      }

    // O += P V (P wave-local rows; lgkmcnt orders write->read within wave)
    __builtin_amdgcn_s_setprio(1);
    #pragma unroll
    for (int ks = 0; ks < 2; ++ks) {
      bf16x8 pf0 = *(const bf16x8*)(sPc + (w * 32 + l15) * 72 + ks * 32 + lh * 8);
      bf16x8 pf1 = *(const bf16x8*)(sPc + (w * 32 + 16 + l15) * 72 + ks * 32 + lh * 8);
      #pragma unroll
      for (int jj = 0; jj < 8; ++jj) {
        bf16x8 vf = *(const bf16x8*)(sV + ((jj * 16 + l15) * 8 + ((ks * 4 + lh) ^ swz)) * 8);
        o[0][jj] = __builtin_amdgcn_mfma_f32_16x16x32_bf16(pf0, vf, o[0][jj], 0, 0, 0);
        o[1][jj] = __builtin_amdgcn_mfma_f32_16x16x32_bf16(pf1, vf, o[1][jj], 0, 0, 0);
      }
    }
    __builtin_amdgcn_s_setprio(0);
    __syncthreads();  // A: PV reads of sP/sV done before next iter's staging overwrites
  }

  #pragma unroll
  for (int i = 0; i < 2; ++i) {
    #pragma unroll
    for (int rg = 0; rg < 4; ++rg) {
      float ls = l_[i][rg];
      ls += __shfl_xor(ls, 1);
      ls += __shfl_xor(ls, 2);
      ls += __shfl_xor(ls, 4);
      ls += __shfl_xor(ls, 8);
      float inv = 1.0f / ls;
      long row = (long)bh * QLEN + qrow0 + i * 16 + lh * 4 + rg;
      #pragma unroll
      for (int jj = 0; jj < 8; ++jj)
        outp[row * VHD + jj * 16 + l15] = o[i][jj][rg] * inv;
    }
  }
}

// ---------------- workspace layout (bytes) ----------------
#define WS_HID_BF   0L
#define WS_WQA_BF   10485760L
#define WS_WQB_BF   32768000L
#define WS_WKVB_BF  108265472L
#define WS_QAN_BF   141819904L
#define WS_CKVN_BF  144965632L
#define WS_Q_BF     146014208L   // part f32 (2x1024x2176x4 = 17.8MB) aliased here first
#define WS_KB_BF    196345856L
#define WS_VT_BF    297009152L
#define WS_FLAGS    364118016L

extern "C" void kernel_launch(void* const* d_in, const int* in_sizes, int n_in,
                              void* d_out, int out_size, void* d_ws, size_t ws_size,
                              hipStream_t stream) {
  const float* hs   = (const float*)d_in[0];
  const float* mask = (const float*)d_in[1];
  const float* pk   = (const float*)d_in[2];
  const float* pv   = (const float*)d_in[3];
  const float* wqa  = (const float*)d_in[4];
  const float* gqa  = (const float*)d_in[5];
  const float* wqb  = (const float*)d_in[6];
  const float* wkva = (const float*)d_in[7];
  const float* gkva = (const float*)d_in[8];
  const float* wkvb = (const float*)d_in[9];

  char* ws = (char*)d_ws;
  unsigned short* hid_bf  = (unsigned short*)(ws + WS_HID_BF);
  unsigned short* wqa_bf  = (unsigned short*)(ws + WS_WQA_BF);
  unsigned short* wkva_bf = wqa_bf + (long)1536 * 5120;
  unsigned short* wpad_bf = wqa_bf + (long)2112 * 5120;
  unsigned short* wqb_bf  = (unsigned short*)(ws + WS_WQB_BF);
  unsigned short* wkvb_bf = (unsigned short*)(ws + WS_WKVB_BF);
  unsigned short* qan_bf  = (unsigned short*)(ws + WS_QAN_BF);
  unsigned short* ckvn_bf = (unsigned short*)(ws + WS_CKVN_BF);
  unsigned short* q_bf    = (unsigned short*)(ws + WS_Q_BF);
  float*          part    = (float*)(ws + WS_Q_BF);
  unsigned short* kb_bf   = (unsigned short*)(ws + WS_KB_BF);
  unsigned short* vt_bf   = (unsigned short*)(ws + WS_VT_BF);
  int*            flags   = (int*)(ws + WS_FLAGS);

  float* out_attn = (float*)d_out;
  float* out_key  = (float*)d_out + 16777216;
  float* out_val  = (float*)d_out + 67108864;

  flags_k<<<128, 256, 0, stream>>>(mask, flags);
  zero_pad_k<<<160, 256, 0, stream>>>(wpad_bf);
  CvtArgs ca;
  ca.src[0] = hs;     ca.dst[0] = hid_bf;
  ca.src[1] = wqa;    ca.dst[1] = wqa_bf;
  ca.src[2] = wkva;   ca.dst[2] = wkva_bf;
  ca.src[3] = wqb;    ca.dst[3] = wqb_bf;
  ca.src[4] = wkvb;   ca.dst[4] = wkvb_bf;
  ca.off[0] = 0; ca.off[1] = 1280; ca.off[2] = 3200; ca.off[3] = 3920;
  ca.off[4] = 13136; ca.off[5] = 17232;
  cvt_all_k<<<17232, 256, 0, stream>>>(ca);
  copy_key_past_k<<<24576, 256, 0, stream>>>(pk, out_key, kb_bf);
  gemm_qa_ckv<<<576, 256, 0, stream>>>(hid_bf, wqa_bf, part);
  post_a_k<<<3072, 256, 0, stream>>>(part, gqa, gkva, qan_bf, ckvn_bf, out_key, kb_bf);
  gemm_bt2<<<3584, 256, 0, stream>>>(qan_bf, wqb_bf, ckvn_bf, wkvb_bf,
                                     q_bf, out_key, out_val, kb_bf, vt_bf);
  vfix_k<<<2048, 256, 0, stream>>>(pv, out_val, vt_bf);
  attn_k<<<1024, 256, 0, stream>>>(q_bf, kb_bf, vt_bf, mask, flags, out_attn);
}

// Round 12
// 581.289 us; speedup vs baseline: 1.9043x; 1.9043x over previous
//
#include <hip/hip_runtime.h>

// ---------------- problem constants ----------------
#define NB    2
#define QLEN  512
#define HIDD  5120
#define QLORA 1536
#define NHEAD 128
#define QHD   192
#define VHD   128
#define KVTOT 1024

typedef float          f32x4   __attribute__((ext_vector_type(4)));
typedef __bf16         bf16x8  __attribute__((ext_vector_type(8)));
typedef unsigned short u16x8   __attribute__((ext_vector_type(8)));
typedef unsigned short u16x4   __attribute__((ext_vector_type(4)));

static __device__ __forceinline__ unsigned short f2bf(float f) {
  union { float f; unsigned u; } v; v.f = f;
  return (unsigned short)((v.u + 0x7fffu + ((v.u >> 16) & 1u)) >> 16);
}

static __device__ __forceinline__ void g2l16(const void* g, void* l) {
  __builtin_amdgcn_global_load_lds(
      (const __attribute__((address_space(1))) void*)g,
      (__attribute__((address_space(3))) void*)l, 16, 0, 0);
}

// ---------------- zero the 64 pad rows of stacked wkva (640 KB) ----------------
__global__ __launch_bounds__(256) void zero_pad_k(unsigned short* __restrict__ dst) {
  int i = blockIdx.x * 256 + threadIdx.x;
  u16x8 z = {0, 0, 0, 0, 0, 0, 0, 0};
  *(u16x8*)(dst + (long)i * 8) = z;
}

// ---------------- merged f32 -> bf16 converts (5 segments) ----------------
struct CvtArgs {
  const float* src[5];
  unsigned short* dst[5];
  int off[6];
};

__global__ __launch_bounds__(256) void cvt_all_k(CvtArgs a) {
  int b = blockIdx.x, s = 0;
  #pragma unroll
  for (int k = 0; k < 4; ++k) if (b >= a.off[k + 1]) s = k + 1;
  long lb = b - a.off[s];
  const float* in = a.src[s];
  unsigned short* out = a.dst[s];
  long base = lb * 1024 + threadIdx.x;
  #pragma unroll
  for (int k = 0; k < 4; ++k) {
    long i = base + k * 256;
    f32x4 v = *(const f32x4*)(in + i * 4);
    u16x4 o;
    o[0] = f2bf(v[0]); o[1] = f2bf(v[1]); o[2] = f2bf(v[2]); o[3] = f2bf(v[3]);
    *(u16x4*)(out + i * 4) = o;
  }
}

// ---------------- mask zero-flags: 1 flag per (b, 128-qtile, 64-ktile) ----------------
__global__ __launch_bounds__(256) void flags_k(const float* __restrict__ mask,
                                               int* __restrict__ flags) {
  int id = blockIdx.x;
  int b = id >> 6, qt = (id >> 4) & 3, kt = id & 15;
  const float* base = mask + (long)b * 524288 + (long)qt * 128 * 1024 + kt * 64;
  int t = threadIdx.x, w = t >> 6;
  unsigned acc = 0;
  #pragma unroll
  for (int i = 0; i < 32; ++i) {
    int e = i * 256 + t;
    int r = e >> 6, c = e & 63;
    union { float f; unsigned u; } v; v.f = base[(long)r * 1024 + c];
    acc |= v.u;
  }
  int any = __any(acc != 0);
  __shared__ int sf[4];
  if ((t & 63) == 0) sf[w] = any;
  __syncthreads();
  if (t == 0) flags[id] = sf[0] | sf[1] | sf[2] | sf[3];
}

// ---------------- fused q_a + ckv GEMM, split-K(2): 128x64 tile, 4 waves ----------------
// 1D grid 576 (pz-space padded 68->72 = 8x9 for BIJECTIVE XCD remap; pz>=68 exits).
__global__ __launch_bounds__(256, 4) void gemm_qa_ckv(const unsigned short* __restrict__ A,
                                                      const unsigned short* __restrict__ Bm,
                                                      float* __restrict__ part) {
  __shared__ __align__(16) unsigned short sA[128 * 64];
  __shared__ __align__(16) unsigned short sB[64 * 64];
  const int t = threadIdx.x, w = t >> 6, l = t & 63;
  const int l15 = l & 15, lh = l >> 4;
  const int swz7 = l15 & 7;
  const int id = blockIdx.x;
  const int xcd = id & 7, slot = id >> 3;
  const int pz = xcd + 8 * (slot >> 3);
  const int mb = slot & 7;
  if (pz >= 68) return;
  const int z = (pz >= 34) ? 1 : 0;
  const int nb = pz - z * 34;
  const unsigned short* Ab = A + (long)mb * 128 * HIDD;
  const unsigned short* Bb = Bm + (long)nb * 64 * HIDD;
  f32x4 acc[2][4];
  #pragma unroll
  for (int i = 0; i < 2; ++i)
    #pragma unroll
    for (int j = 0; j < 4; ++j)
      #pragma unroll
      for (int r = 0; r < 4; ++r) acc[i][j][r] = 0.f;

  const int k0 = z * 2560;
  for (int kt = k0; kt < k0 + 2560; kt += 64) {
    #pragma unroll
    for (int i2 = 0; i2 < 4; ++i2) {
      int n = i2 * 256 + t, r = n >> 3, c = (n & 7) ^ (r & 7);
      g2l16(Ab + (long)r * HIDD + kt + c * 8, (char*)sA + (i2 * 256 + w * 64) * 16);
    }
    #pragma unroll
    for (int i2 = 0; i2 < 2; ++i2) {
      int n = i2 * 256 + t, r = n >> 3, c = (n & 7) ^ (r & 7);
      g2l16(Bb + (long)r * HIDD + kt + c * 8, (char*)sB + (i2 * 256 + w * 64) * 16);
    }
    __syncthreads();
    #pragma unroll
    for (int ks = 0; ks < 2; ++ks) {
      bf16x8 af[2], bfr[4];
      #pragma unroll
      for (int i = 0; i < 2; ++i)
        af[i] = *(const bf16x8*)(sA + (w * 32 + i * 16 + l15) * 64 + ((ks * 4 + lh) ^ swz7) * 8);
      #pragma unroll
      for (int j = 0; j < 4; ++j)
        bfr[j] = *(const bf16x8*)(sB + (j * 16 + l15) * 64 + ((ks * 4 + lh) ^ swz7) * 8);
      #pragma unroll
      for (int i = 0; i < 2; ++i)
        #pragma unroll
        for (int j = 0; j < 4; ++j)
          acc[i][j] = __builtin_amdgcn_mfma_f32_16x16x32_bf16(af[i], bfr[j], acc[i][j], 0, 0, 0);
    }
    __syncthreads();
  }
  float* po = part + (long)z * 1024 * 2176;
  const int colbase = nb * 64;
  #pragma unroll
  for (int i = 0; i < 2; ++i)
    #pragma unroll
    for (int j = 0; j < 4; ++j) {
      const int col = colbase + j * 16 + l15;
      #pragma unroll
      for (int r4 = 0; r4 < 4; ++r4) {
        const long row = (long)mb * 128 + w * 32 + i * 16 + lh * 4 + r4;
        po[row * 2176 + col] = acc[i][j][r4];
      }
    }
}

// ---------------- fused rmsnorm(q_a) + rmsnorm(ckv) + k_pe broadcast (2 partials) ------
__global__ __launch_bounds__(256) void post_a_k(const float* __restrict__ part,
                                                const float* __restrict__ gq,
                                                const float* __restrict__ gkv,
                                                unsigned short* __restrict__ qan,
                                                unsigned short* __restrict__ ckvn,
                                                float* __restrict__ kout,
                                                unsigned short* __restrict__ kb) {
  const long ZS = 1024L * 2176;
  int bid = blockIdx.x, t = threadIdx.x;
  if (bid >= 2048) {  // k_pe broadcast
    int row = bid - 2048;
    int j = t & 63, h0 = t >> 6;
    const float* p = part + (long)row * 2176 + 2048 + j;
    float v = p[0] + p[ZS];
    unsigned short vb = f2bf(v);
    long b_ = row >> 9, qi = row & 511;
    for (int h = h0; h < NHEAD; h += 4) {
      long idx = ((b_ * NHEAD + h) * KVTOT + 512 + qi) * QHD + 128 + j;
      kout[idx] = v;
      kb[idx] = vb;
    }
    return;
  }
  bool isQ = bid < 1024;
  int row = isQ ? bid : bid - 1024;
  int cols = isQ ? 1536 : 512;
  const float* g = isQ ? gq : gkv;
  unsigned short* out = isQ ? (qan + (long)row * 1536) : (ckvn + (long)row * 512);
  const float* x = part + (long)row * 2176 + (isQ ? 0 : 1536);
  int w = t >> 6, l = t & 63;
  float xv[6];
  int nc = cols >> 8;
  float ss = 0.f;
  for (int i = 0; i < nc; ++i) {
    int c = t + i * 256;
    float v = x[c] + x[c + ZS];
    xv[i] = v; ss += v * v;
  }
  #pragma unroll
  for (int m = 32; m >= 1; m >>= 1) ss += __shfl_xor(ss, m);
  __shared__ float red[4];
  if (l == 0) red[w] = ss;
  __syncthreads();
  float tot = red[0] + red[1] + red[2] + red[3];
  float rs = rsqrtf(tot / (float)cols + 1e-6f);
  for (int i = 0; i < nc; ++i) {
    int c = t + i * 256;
    out[c] = f2bf(g[c] * xv[i] * rs);
  }
}

// ---------------- merged Q-GEMM + KV-GEMM: 128x128 tile, BK=64, 4 waves ----------------
__global__ __launch_bounds__(256, 4) void gemm_bt2(const unsigned short* __restrict__ Aq,
                                                   const unsigned short* __restrict__ Bq,
                                                   const unsigned short* __restrict__ Akv,
                                                   const unsigned short* __restrict__ Bkv,
                                                   unsigned short* __restrict__ qout,
                                                   float* __restrict__ kout,
                                                   float* __restrict__ vout,
                                                   unsigned short* __restrict__ kb,
                                                   unsigned short* __restrict__ vt) {
  __shared__ __align__(16) unsigned short sA[128 * 64];
  __shared__ __align__(16) unsigned short sB[128 * 64];
  const int t = threadIdx.x, w = t >> 6, l = t & 63;
  const int l15 = l & 15, lh = l >> 4;
  const int swz7 = l15 & 7;
  const int wm = w >> 1, wn = w & 1;
  const int id = blockIdx.x;
  const int xcd = id & 7, slot = id >> 3;
  const int y = xcd + 8 * (slot >> 3);
  const int mb = slot & 7;
  const bool isQ = y < 192;
  const int nb = isQ ? y : y - 192;
  const int K = isQ ? QLORA : 512;
  const unsigned short* Ab = (isQ ? Aq : Akv) + (long)mb * 128 * K;
  const unsigned short* Bb = (isQ ? Bq : Bkv) + (long)nb * 128 * K;
  f32x4 acc[4][4];
  #pragma unroll
  for (int i = 0; i < 4; ++i)
    #pragma unroll
    for (int j = 0; j < 4; ++j)
      #pragma unroll
      for (int r = 0; r < 4; ++r) acc[i][j][r] = 0.f;

  const int srow = l >> 3;
  const int scol = ((l & 7) ^ srow) * 8;

  for (int kt = 0; kt < K; kt += 64) {
    #pragma unroll
    for (int i = 0; i < 4; ++i) {
      const int chunk = i * 4 + w;
      const int r = chunk * 8 + srow;
      g2l16(Ab + (long)r * K + kt + scol, (char*)sA + chunk * 1024);
      g2l16(Bb + (long)r * K + kt + scol, (char*)sB + chunk * 1024);
    }
    __syncthreads();
    #pragma unroll
    for (int ks = 0; ks < 2; ++ks) {
      bf16x8 af[4], bfr[4];
      #pragma unroll
      for (int i = 0; i < 4; ++i)
        af[i] = *(const bf16x8*)(sA + (wm * 64 + i * 16 + l15) * 64 + ((ks * 4 + lh) ^ swz7) * 8);
      #pragma unroll
      for (int j = 0; j < 4; ++j)
        bfr[j] = *(const bf16x8*)(sB + (wn * 64 + j * 16 + l15) * 64 + ((ks * 4 + lh) ^ swz7) * 8);
      #pragma unroll
      for (int i = 0; i < 4; ++i)
        #pragma unroll
        for (int j = 0; j < 4; ++j)
          acc[i][j] = __builtin_amdgcn_mfma_f32_16x16x32_bf16(af[i], bfr[j], acc[i][j], 0, 0, 0);
    }
    __syncthreads();
  }

  const long rowbase = (long)mb * 128 + wm * 64;
  const long b_ = rowbase >> 9;
  const int colbase = nb * 128 + wn * 64;
  #pragma unroll
  for (int i = 0; i < 4; ++i) {
    const long qi0 = (rowbase + i * 16 + lh * 4) & 511;
    #pragma unroll
    for (int j = 0; j < 4; ++j) {
      const int col = colbase + j * 16 + l15;
      if (isQ) {
        const int h = col / QHD, d = col - h * QHD;
        unsigned short* qp = qout + ((b_ * NHEAD + h) * QLEN + qi0) * QHD + d;
        #pragma unroll
        for (int r4 = 0; r4 < 4; ++r4) qp[(long)r4 * QHD] = f2bf(acc[i][j][r4]);
      } else {
        const int h = col >> 8, d = col & 255;
        if (d < 128) {
          const long idx = ((b_ * NHEAD + h) * KVTOT + 512 + qi0) * QHD + d;
          #pragma unroll
          for (int r4 = 0; r4 < 4; ++r4) {
            kout[idx + (long)r4 * QHD] = acc[i][j][r4];
            kb[idx + (long)r4 * QHD] = f2bf(acc[i][j][r4]);
          }
        } else {
          const int dv = d - 128;
          float* vp = vout + ((b_ * NHEAD + h) * KVTOT + 512 + qi0) * VHD + dv;
          u16x4 tv;
          #pragma unroll
          for (int r4 = 0; r4 < 4; ++r4) {
            vp[(long)r4 * VHD] = acc[i][j][r4];
            tv[r4] = f2bf(acc[i][j][r4]);
          }
          *(u16x4*)(vt + ((b_ * NHEAD + h) * VHD + dv) * KVTOT + 512 + qi0) = tv;
        }
      }
    }
  }
}

// ---------------- past key copy: f32 out + bf16 ws ----------------
__global__ __launch_bounds__(256) void copy_key_past_k(const float* __restrict__ pk,
                                                       float* __restrict__ kout,
                                                       unsigned short* __restrict__ kb) {
  long i4 = (long)blockIdx.x * 256 + threadIdx.x;
  f32x4 v = *(const f32x4*)(pk + i4 * 4);
  long e = i4 * 4;
  long bh = e / 98304;
  long rem = e - bh * 98304;
  long oidx = bh * 196608 + rem;
  *(f32x4*)(kout + oidx) = v;
  u16x4 b;
  b[0] = f2bf(v[0]); b[1] = f2bf(v[1]); b[2] = f2bf(v[2]); b[3] = f2bf(v[3]);
  *(u16x4*)(kb + oidx) = b;
}

// ---------------- V past rows only: copy pv -> out_val + transpose -> Vt bf16 ----------
__global__ __launch_bounds__(256) void vfix_k(const float* __restrict__ pv,
                                              float* __restrict__ outv,
                                              unsigned short* __restrict__ vt) {
  __shared__ __align__(16) unsigned short sT[128 * 72];
  int bh = blockIdx.x >> 3, kt = blockIdx.x & 7;
  int t = threadIdx.x;
  const float* src = pv + ((long)bh * 512 + kt * 64) * VHD;
  float* dstv = outv + ((long)bh * KVTOT + kt * 64) * VHD;
  #pragma unroll
  for (int i = 0; i < 8; ++i) {
    int id = t + i * 256;
    int r = id >> 5, c4 = (id & 31) * 4;
    f32x4 v = *(const f32x4*)(src + (long)r * VHD + c4);
    *(f32x4*)(dstv + (long)r * VHD + c4) = v;
    #pragma unroll
    for (int jj = 0; jj < 4; ++jj) sT[(c4 + jj) * 72 + r] = f2bf(v[jj]);
  }
  __syncthreads();
  #pragma unroll
  for (int i = 0; i < 4; ++i) {
    int id = t + i * 256;
    int d = id >> 3, c = id & 7;
    u16x8 v = *(const u16x8*)(sT + d * 72 + c * 8);
    *(u16x8*)(vt + ((long)bh * VHD + d) * KVTOT + kt * 64 + c * 8) = v;
  }
}

// ---------------- attention staging helpers (XOR-swizzled source, linear LDS dest) ----
static __device__ __forceinline__ void stage_k_tile(const unsigned short* __restrict__ src,
                                                    char* dstbase, int t) {
  const int w = t >> 6;
  #pragma unroll
  for (int i2 = 0; i2 < 6; ++i2) {
    int n = i2 * 256 + t;
    int r = n / 24, cp = n - r * 24;
    int c = cp ^ (r & 7);
    g2l16(src + (long)r * QHD + c * 8, dstbase + (i2 * 256 + w * 64) * 16);
  }
}

static __device__ __forceinline__ void stage_v_tile(const unsigned short* __restrict__ src,
                                                    char* dstbase, int t) {
  const int w = t >> 6;
  #pragma unroll
  for (int i2 = 0; i2 < 4; ++i2) {
    int n = i2 * 256 + t;
    int r = n >> 3, cp = n & 7;
    int c = cp ^ (r & 7);
    g2l16(src + (long)r * KVTOT + c * 8, dstbase + (i2 * 256 + w * 64) * 16);
  }
}

// ---------------- flash attention: 1 block = (b,h, 128-row q tile), 4 waves ------------
// 40 KB single-K-buffer structure (round 11) with the SPILL FIXED: launch_bounds(256,2)
// restores the 128-VGPR allocation (round-11's (256,4) forced 64 VGPR -> 2.6 GB scratch).
// LDS 40 KB -> up to 4 blocks/CU at VGPR<=128.
__global__ __launch_bounds__(256, 2) void attn_k(const unsigned short* __restrict__ Qw,
                                                 const unsigned short* __restrict__ Kb,
                                                 const unsigned short* __restrict__ Vt,
                                                 const float* __restrict__ mask,
                                                 const int* __restrict__ flags,
                                                 float* __restrict__ outp) {
  __shared__ __align__(16) unsigned short sK[64 * 192];   // 24 KB; doubles as sP after QK
  __shared__ __align__(16) unsigned short sV[128 * 64];   // 16 KB
  const int t = threadIdx.x, w = t >> 6, l = t & 63;
  const int l15 = l & 15, lh = l >> 4;
  const int raw = blockIdx.x;
  const int xcd = raw & 7, slot = raw >> 3;
  const int bh = xcd * 32 + (slot >> 2), qt = slot & 3;
  const long b_ = bh >> 7;
  const float SCALE = 0.051023330039633184f;
  const int swz = l15 & 7;

  bf16x8 qf[2][6];
  const unsigned short* Qb = Qw + ((long)bh * QLEN + qt * 128 + w * 32) * QHD;
  #pragma unroll
  for (int i = 0; i < 2; ++i)
    #pragma unroll
    for (int ks = 0; ks < 6; ++ks)
      qf[i][ks] = *(const bf16x8*)(Qb + (i * 16 + l15) * QHD + ks * 32 + lh * 8);

  f32x4 o[2][8];
  #pragma unroll
  for (int i = 0; i < 2; ++i)
    #pragma unroll
    for (int j = 0; j < 8; ++j)
      #pragma unroll
      for (int r = 0; r < 4; ++r) o[i][j][r] = 0.f;
  float m_[2][4], l_[2][4];  // l_ per-lane partial, reduced in epilogue
  #pragma unroll
  for (int i = 0; i < 2; ++i)
    #pragma unroll
    for (int r = 0; r < 4; ++r) { m_[i][r] = -1e30f; l_[i][r] = 0.f; }

  const int qrow0 = qt * 128 + w * 32;
  const unsigned short* Kbh = Kb + (long)bh * KVTOT * QHD;
  const unsigned short* Vbh = Vt + (long)bh * VHD * KVTOT;
  const float* mrow = mask + b_ * 524288 + (long)(qrow0 + lh * 4) * 1024 + l15;
  const int fbase = (int)b_ * 64 + qt * 16;

  for (int kt = 0; kt < 16; ++kt) {
    // stage this tile's K and V (async, drained at barrier B)
    stage_k_tile(Kbh + (long)kt * 64 * QHD, (char*)sK, t);
    stage_v_tile(Vbh + kt * 64, (char*)sV, t);
    const int flag = flags[fbase + kt];
    __syncthreads();  // B: staging drained (vmcnt(0))

    // S = Q K^T (swizzled sK reads)
    f32x4 s[2][4];
    #pragma unroll
    for (int i = 0; i < 2; ++i)
      #pragma unroll
      for (int j = 0; j < 4; ++j)
        #pragma unroll
        for (int r = 0; r < 4; ++r) s[i][j][r] = 0.f;
    __builtin_amdgcn_s_setprio(1);
    #pragma unroll
    for (int j = 0; j < 4; ++j) {
      #pragma unroll
      for (int ks = 0; ks < 6; ++ks) {
        bf16x8 kf = *(const bf16x8*)(sK + ((j * 16 + l15) * 24 + ((ks * 4 + lh) ^ swz)) * 8);
        s[0][j] = __builtin_amdgcn_mfma_f32_16x16x32_bf16(qf[0][ks], kf, s[0][j], 0, 0, 0);
        s[1][j] = __builtin_amdgcn_mfma_f32_16x16x32_bf16(qf[1][ks], kf, s[1][j], 0, 0, 0);
      }
    }
    __builtin_amdgcn_s_setprio(0);

    // online softmax
    unsigned short pk16[2][4][4];
    #pragma unroll
    for (int i = 0; i < 2; ++i) {
      #pragma unroll
      for (int rg = 0; rg < 4; ++rg) {
        float sc[4];
        if (flag) {
          #pragma unroll
          for (int j = 0; j < 4; ++j)
            sc[j] = s[i][j][rg] * SCALE + mrow[(long)(i * 16 + rg) * 1024 + kt * 64 + j * 16];
        } else {
          #pragma unroll
          for (int j = 0; j < 4; ++j) sc[j] = s[i][j][rg] * SCALE;
        }
        float mx = fmaxf(fmaxf(sc[0], sc[1]), fmaxf(sc[2], sc[3]));
        mx = fmaxf(mx, __shfl_xor(mx, 1));
        mx = fmaxf(mx, __shfl_xor(mx, 2));
        mx = fmaxf(mx, __shfl_xor(mx, 4));
        mx = fmaxf(mx, __shfl_xor(mx, 8));
        float mo = m_[i][rg];
        float mn = fmaxf(mo, mx);
        if (__any(mn > mo)) {
          float al = __expf(mo - mn);
          #pragma unroll
          for (int jj = 0; jj < 8; ++jj) o[i][jj][rg] *= al;
          l_[i][rg] *= al;
          m_[i][rg] = mn;
        }
        float ps = 0.f;
        #pragma unroll
        for (int j = 0; j < 4; ++j) {
          float p = __expf(sc[j] - m_[i][rg]);
          ps += p;
          pk16[i][rg][j] = f2bf(p);
        }
        l_[i][rg] += ps;
      }
    }
    __syncthreads();  // C: all QK^T reads of sK done -> safe to overwrite as sP

    // write P into sK space (stride 72, 18.4 KB < 24 KB)
    unsigned short* sPc = (unsigned short*)sK;
    #pragma unroll
    for (int i = 0; i < 2; ++i)
      #pragma unroll
      for (int rg = 0; rg < 4; ++rg) {
        const int prow = w * 32 + i * 16 + lh * 4 + rg;
        #pragma unroll
        for (int j = 0; j < 4; ++j)
          sPc[prow * 72 + j * 16 + l15] = pk16[i][rg][j];
      }

    // O += P V (P wave-local rows; lgkmcnt orders write->read within wave)
    __builtin_amdgcn_s_setprio(1);
    #pragma unroll
    for (int ks = 0; ks < 2; ++ks) {
      bf16x8 pf0 = *(const bf16x8*)(sPc + (w * 32 + l15) * 72 + ks * 32 + lh * 8);
      bf16x8 pf1 = *(const bf16x8*)(sPc + (w * 32 + 16 + l15) * 72 + ks * 32 + lh * 8);
      #pragma unroll
      for (int jj = 0; jj < 8; ++jj) {
        bf16x8 vf = *(const bf16x8*)(sV + ((jj * 16 + l15) * 8 + ((ks * 4 + lh) ^ swz)) * 8);
        o[0][jj] = __builtin_amdgcn_mfma_f32_16x16x32_bf16(pf0, vf, o[0][jj], 0, 0, 0);
        o[1][jj] = __builtin_amdgcn_mfma_f32_16x16x32_bf16(pf1, vf, o[1][jj], 0, 0, 0);
      }
    }
    __builtin_amdgcn_s_setprio(0);
    __syncthreads();  // A: PV reads of sP/sV done before next iter's staging overwrites
  }

  #pragma unroll
  for (int i = 0; i < 2; ++i) {
    #pragma unroll
    for (int rg = 0; rg < 4; ++rg) {
      float ls = l_[i][rg];
      ls += __shfl_xor(ls, 1);
      ls += __shfl_xor(ls, 2);
      ls += __shfl_xor(ls, 4);
      ls += __shfl_xor(ls, 8);
      float inv = 1.0f / ls;
      long row = (long)bh * QLEN + qrow0 + i * 16 + lh * 4 + rg;
      #pragma unroll
      for (int jj = 0; jj < 8; ++jj)
        outp[row * VHD + jj * 16 + l15] = o[i][jj][rg] * inv;
    }
  }
}

// ---------------- workspace layout (bytes) ----------------
#define WS_HID_BF   0L
#define WS_WQA_BF   10485760L
#define WS_WQB_BF   32768000L
#define WS_WKVB_BF  108265472L
#define WS_QAN_BF   141819904L
#define WS_CKVN_BF  144965632L
#define WS_Q_BF     146014208L   // part f32 (2x1024x2176x4 = 17.8MB) aliased here first
#define WS_KB_BF    196345856L
#define WS_VT_BF    297009152L
#define WS_FLAGS    364118016L

extern "C" void kernel_launch(void* const* d_in, const int* in_sizes, int n_in,
                              void* d_out, int out_size, void* d_ws, size_t ws_size,
                              hipStream_t stream) {
  const float* hs   = (const float*)d_in[0];
  const float* mask = (const float*)d_in[1];
  const float* pk   = (const float*)d_in[2];
  const float* pv   = (const float*)d_in[3];
  const float* wqa  = (const float*)d_in[4];
  const float* gqa  = (const float*)d_in[5];
  const float* wqb  = (const float*)d_in[6];
  const float* wkva = (const float*)d_in[7];
  const float* gkva = (const float*)d_in[8];
  const float* wkvb = (const float*)d_in[9];

  char* ws = (char*)d_ws;
  unsigned short* hid_bf  = (unsigned short*)(ws + WS_HID_BF);
  unsigned short* wqa_bf  = (unsigned short*)(ws + WS_WQA_BF);
  unsigned short* wkva_bf = wqa_bf + (long)1536 * 5120;
  unsigned short* wpad_bf = wqa_bf + (long)2112 * 5120;
  unsigned short* wqb_bf  = (unsigned short*)(ws + WS_WQB_BF);
  unsigned short* wkvb_bf = (unsigned short*)(ws + WS_WKVB_BF);
  unsigned short* qan_bf  = (unsigned short*)(ws + WS_QAN_BF);
  unsigned short* ckvn_bf = (unsigned short*)(ws + WS_CKVN_BF);
  unsigned short* q_bf    = (unsigned short*)(ws + WS_Q_BF);
  float*          part    = (float*)(ws + WS_Q_BF);
  unsigned short* kb_bf   = (unsigned short*)(ws + WS_KB_BF);
  unsigned short* vt_bf   = (unsigned short*)(ws + WS_VT_BF);
  int*            flags   = (int*)(ws + WS_FLAGS);

  float* out_attn = (float*)d_out;
  float* out_key  = (float*)d_out + 16777216;
  float* out_val  = (float*)d_out + 67108864;

  flags_k<<<128, 256, 0, stream>>>(mask, flags);
  zero_pad_k<<<160, 256, 0, stream>>>(wpad_bf);
  CvtArgs ca;
  ca.src[0] = hs;     ca.dst[0] = hid_bf;
  ca.src[1] = wqa;    ca.dst[1] = wqa_bf;
  ca.src[2] = wkva;   ca.dst[2] = wkva_bf;
  ca.src[3] = wqb;    ca.dst[3] = wqb_bf;
  ca.src[4] = wkvb;   ca.dst[4] = wkvb_bf;
  ca.off[0] = 0; ca.off[1] = 1280; ca.off[2] = 3200; ca.off[3] = 3920;
  ca.off[4] = 13136; ca.off[5] = 17232;
  cvt_all_k<<<17232, 256, 0, stream>>>(ca);
  copy_key_past_k<<<24576, 256, 0, stream>>>(pk, out_key, kb_bf);
  gemm_qa_ckv<<<576, 256, 0, stream>>>(hid_bf, wqa_bf, part);
  post_a_k<<<3072, 256, 0, stream>>>(part, gqa, gkva, qan_bf, ckvn_bf, out_key, kb_bf);
  gemm_bt2<<<3584, 256, 0, stream>>>(qan_bf, wqb_bf, ckvn_bf, wkvb_bf,
                                     q_bf, out_key, out_val, kb_bf, vt_bf);
  vfix_k<<<2048, 256, 0, stream>>>(pv, out_val, vt_bf);
  attn_k<<<1024, 256, 0, stream>>>(q_bf, kb_bf, vt_bf, mask, flags, out_attn);
}

// Round 13
// 537.335 us; speedup vs baseline: 2.0600x; 1.0818x over previous
//
#include <hip/hip_runtime.h>

// ---------------- problem constants ----------------
#define NB    2
#define QLEN  512
#define HIDD  5120
#define QLORA 1536
#define NHEAD 128
#define QHD   192
#define VHD   128
#define KVTOT 1024

typedef float          f32x4   __attribute__((ext_vector_type(4)));
typedef __bf16         bf16x8  __attribute__((ext_vector_type(8)));
typedef unsigned short u16x8   __attribute__((ext_vector_type(8)));
typedef unsigned short u16x4   __attribute__((ext_vector_type(4)));

static __device__ __forceinline__ unsigned short f2bf(float f) {
  union { float f; unsigned u; } v; v.f = f;
  return (unsigned short)((v.u + 0x7fffu + ((v.u >> 16) & 1u)) >> 16);
}

static __device__ __forceinline__ void g2l16(const void* g, void* l) {
  __builtin_amdgcn_global_load_lds(
      (const __attribute__((address_space(1))) void*)g,
      (__attribute__((address_space(3))) void*)l, 16, 0, 0);
}

// ---------------- prep kernel: cvt(hs,wqa,wkva) + mask flags + pad-zero ----------------
// ids [0,1280) hs | [1280,3200) wqa | [3200,3920) wkva | [3920,4048) flags | [4048,4208) pad
__global__ __launch_bounds__(256) void prep_k(const float* __restrict__ hs,
                                              unsigned short* __restrict__ hid,
                                              const float* __restrict__ wqa,
                                              unsigned short* __restrict__ wqaB,
                                              const float* __restrict__ wkva,
                                              unsigned short* __restrict__ wkvaB,
                                              const float* __restrict__ mask,
                                              int* __restrict__ flags,
                                              unsigned short* __restrict__ pad) {
  __shared__ int sf[4];
  const int gid = blockIdx.x, t = threadIdx.x;
  if (gid < 3920) {
    const float* in; unsigned short* out; long lb;
    if (gid < 1280)      { in = hs;   out = hid;   lb = gid; }
    else if (gid < 3200) { in = wqa;  out = wqaB;  lb = gid - 1280; }
    else                 { in = wkva; out = wkvaB; lb = gid - 3200; }
    long base = lb * 1024 + t;
    #pragma unroll
    for (int k = 0; k < 4; ++k) {
      long i = base + k * 256;
      f32x4 v = *(const f32x4*)(in + i * 4);
      u16x4 o;
      o[0] = f2bf(v[0]); o[1] = f2bf(v[1]); o[2] = f2bf(v[2]); o[3] = f2bf(v[3]);
      *(u16x4*)(out + i * 4) = o;
    }
  } else if (gid < 4048) {
    int id = gid - 3920;  // b*64 + qt*16 + kt
    int b = id >> 6, qt = (id >> 4) & 3, kt = id & 15;
    const float* base = mask + (long)b * 524288 + (long)qt * 128 * 1024 + kt * 64;
    int w = t >> 6;
    unsigned acc = 0;
    #pragma unroll
    for (int i = 0; i < 32; ++i) {
      int e = i * 256 + t;
      int r = e >> 6, c = e & 63;
      union { float f; unsigned u; } v; v.f = base[(long)r * 1024 + c];
      acc |= v.u;
    }
    int any = __any(acc != 0);
    if ((t & 63) == 0) sf[w] = any;
    __syncthreads();
    if (t == 0) flags[id] = sf[0] | sf[1] | sf[2] | sf[3];
  } else {
    int i = (gid - 4048) * 256 + t;
    u16x8 z = {0, 0, 0, 0, 0, 0, 0, 0};
    *(u16x8*)(pad + (long)i * 8) = z;
  }
}

// ---------------- MEGA kernel 1: qa_ckv GEMM + cvt(wqb,wkvb) + copy_key + vfix ----------
// ids [0,576): qa_ckv split-K(2), XCD-remapped (id math preserved at offset 0)
// ids [576,13888): cvt wqb (9216) then wkvb (4096)
// ids [13888,38464): past-key copy (24576)
// ids [38464,40512): V past copy+transpose (2048)
// GEMM blocks dispatch first -> compute co-schedules with the BW blocks saturating HBM.
__global__ __launch_bounds__(256, 4) void mega1_k(
    const unsigned short* __restrict__ A, const unsigned short* __restrict__ Bm,
    float* __restrict__ part,
    const float* __restrict__ wqbF, unsigned short* __restrict__ wqbB,
    const float* __restrict__ wkvbF, unsigned short* __restrict__ wkvbB,
    const float* __restrict__ pk, float* __restrict__ kout, unsigned short* __restrict__ kb,
    const float* __restrict__ pv, float* __restrict__ outv, unsigned short* __restrict__ vt) {
  __shared__ __align__(16) char smem[24576];
  const int gid = blockIdx.x, t = threadIdx.x;

  if (gid < 576) {
    // ---- fused q_a + ckv GEMM, split-K(2), bijective XCD remap (pz padded to 72) ----
    unsigned short* sA = (unsigned short*)smem;            // 128*64 = 16384 B
    unsigned short* sB = (unsigned short*)(smem + 16384);  // 64*64  =  8192 B
    const int w = t >> 6, l = t & 63;
    const int l15 = l & 15, lh = l >> 4;
    const int swz7 = l15 & 7;
    const int xcd = gid & 7, slot = gid >> 3;
    const int pz = xcd + 8 * (slot >> 3);
    const int mb = slot & 7;
    if (pz >= 68) return;
    const int z = (pz >= 34) ? 1 : 0;
    const int nb = pz - z * 34;
    const unsigned short* Ab = A + (long)mb * 128 * HIDD;
    const unsigned short* Bb = Bm + (long)nb * 64 * HIDD;
    f32x4 acc[2][4];
    #pragma unroll
    for (int i = 0; i < 2; ++i)
      #pragma unroll
      for (int j = 0; j < 4; ++j)
        #pragma unroll
        for (int r = 0; r < 4; ++r) acc[i][j][r] = 0.f;

    const int k0 = z * 2560;
    for (int kt = k0; kt < k0 + 2560; kt += 64) {
      #pragma unroll
      for (int i2 = 0; i2 < 4; ++i2) {
        int n = i2 * 256 + t, r = n >> 3, c = (n & 7) ^ (r & 7);
        g2l16(Ab + (long)r * HIDD + kt + c * 8, (char*)sA + (i2 * 256 + w * 64) * 16);
      }
      #pragma unroll
      for (int i2 = 0; i2 < 2; ++i2) {
        int n = i2 * 256 + t, r = n >> 3, c = (n & 7) ^ (r & 7);
        g2l16(Bb + (long)r * HIDD + kt + c * 8, (char*)sB + (i2 * 256 + w * 64) * 16);
      }
      __syncthreads();
      #pragma unroll
      for (int ks = 0; ks < 2; ++ks) {
        bf16x8 af[2], bfr[4];
        #pragma unroll
        for (int i = 0; i < 2; ++i)
          af[i] = *(const bf16x8*)(sA + (w * 32 + i * 16 + l15) * 64 + ((ks * 4 + lh) ^ swz7) * 8);
        #pragma unroll
        for (int j = 0; j < 4; ++j)
          bfr[j] = *(const bf16x8*)(sB + (j * 16 + l15) * 64 + ((ks * 4 + lh) ^ swz7) * 8);
        #pragma unroll
        for (int i = 0; i < 2; ++i)
          #pragma unroll
          for (int j = 0; j < 4; ++j)
            acc[i][j] = __builtin_amdgcn_mfma_f32_16x16x32_bf16(af[i], bfr[j], acc[i][j], 0, 0, 0);
      }
      __syncthreads();
    }
    float* po = part + (long)z * 1024 * 2176;
    const int colbase = nb * 64;
    #pragma unroll
    for (int i = 0; i < 2; ++i)
      #pragma unroll
      for (int j = 0; j < 4; ++j) {
        const int col = colbase + j * 16 + l15;
        #pragma unroll
        for (int r4 = 0; r4 < 4; ++r4) {
          const long row = (long)mb * 128 + w * 32 + i * 16 + lh * 4 + r4;
          po[row * 2176 + col] = acc[i][j][r4];
        }
      }
  } else if (gid < 13888) {
    // ---- cvt wqb / wkvb ----
    long lb = gid - 576;
    const float* in; unsigned short* out;
    if (lb < 9216) { in = wqbF; out = wqbB; }
    else           { in = wkvbF; out = wkvbB; lb -= 9216; }
    long base = lb * 1024 + t;
    #pragma unroll
    for (int k = 0; k < 4; ++k) {
      long i = base + k * 256;
      f32x4 v = *(const f32x4*)(in + i * 4);
      u16x4 o;
      o[0] = f2bf(v[0]); o[1] = f2bf(v[1]); o[2] = f2bf(v[2]); o[3] = f2bf(v[3]);
      *(u16x4*)(out + i * 4) = o;
    }
  } else if (gid < 38464) {
    // ---- past key copy: f32 out + bf16 ws ----
    long i4 = (long)(gid - 13888) * 256 + t;
    f32x4 v = *(const f32x4*)(pk + i4 * 4);
    long e = i4 * 4;
    long bh = e / 98304;
    long rem = e - bh * 98304;
    long oidx = bh * 196608 + rem;
    *(f32x4*)(kout + oidx) = v;
    u16x4 b;
    b[0] = f2bf(v[0]); b[1] = f2bf(v[1]); b[2] = f2bf(v[2]); b[3] = f2bf(v[3]);
    *(u16x4*)(kb + oidx) = b;
  } else {
    // ---- V past rows: copy pv -> out_val + transpose -> Vt bf16 ----
    unsigned short* sT = (unsigned short*)smem;  // 128*72*2 = 18432 B
    int lid = gid - 38464;
    int bh = lid >> 3, kt = lid & 7;
    const float* src = pv + ((long)bh * 512 + kt * 64) * VHD;
    float* dstv = outv + ((long)bh * KVTOT + kt * 64) * VHD;
    #pragma unroll
    for (int i = 0; i < 8; ++i) {
      int id = t + i * 256;
      int r = id >> 5, c4 = (id & 31) * 4;
      f32x4 v = *(const f32x4*)(src + (long)r * VHD + c4);
      *(f32x4*)(dstv + (long)r * VHD + c4) = v;
      #pragma unroll
      for (int jj = 0; jj < 4; ++jj) sT[(c4 + jj) * 72 + r] = f2bf(v[jj]);
    }
    __syncthreads();
    #pragma unroll
    for (int i = 0; i < 4; ++i) {
      int id = t + i * 256;
      int d = id >> 3, c = id & 7;
      u16x8 v = *(const u16x8*)(sT + d * 72 + c * 8);
      *(u16x8*)(vt + ((long)bh * VHD + d) * KVTOT + kt * 64 + c * 8) = v;
    }
  }
}

// ---------------- fused rmsnorm(q_a) + rmsnorm(ckv) + k_pe broadcast (2 partials) ------
__global__ __launch_bounds__(256) void post_a_k(const float* __restrict__ part,
                                                const float* __restrict__ gq,
                                                const float* __restrict__ gkv,
                                                unsigned short* __restrict__ qan,
                                                unsigned short* __restrict__ ckvn,
                                                float* __restrict__ kout,
                                                unsigned short* __restrict__ kb) {
  const long ZS = 1024L * 2176;
  int bid = blockIdx.x, t = threadIdx.x;
  if (bid >= 2048) {  // k_pe broadcast
    int row = bid - 2048;
    int j = t & 63, h0 = t >> 6;
    const float* p = part + (long)row * 2176 + 2048 + j;
    float v = p[0] + p[ZS];
    unsigned short vb = f2bf(v);
    long b_ = row >> 9, qi = row & 511;
    for (int h = h0; h < NHEAD; h += 4) {
      long idx = ((b_ * NHEAD + h) * KVTOT + 512 + qi) * QHD + 128 + j;
      kout[idx] = v;
      kb[idx] = vb;
    }
    return;
  }
  bool isQ = bid < 1024;
  int row = isQ ? bid : bid - 1024;
  int cols = isQ ? 1536 : 512;
  const float* g = isQ ? gq : gkv;
  unsigned short* out = isQ ? (qan + (long)row * 1536) : (ckvn + (long)row * 512);
  const float* x = part + (long)row * 2176 + (isQ ? 0 : 1536);
  int w = t >> 6, l = t & 63;
  float xv[6];
  int nc = cols >> 8;
  float ss = 0.f;
  for (int i = 0; i < nc; ++i) {
    int c = t + i * 256;
    float v = x[c] + x[c + ZS];
    xv[i] = v; ss += v * v;
  }
  #pragma unroll
  for (int m = 32; m >= 1; m >>= 1) ss += __shfl_xor(ss, m);
  __shared__ float red[4];
  if (l == 0) red[w] = ss;
  __syncthreads();
  float tot = red[0] + red[1] + red[2] + red[3];
  float rs = rsqrtf(tot / (float)cols + 1e-6f);
  for (int i = 0; i < nc; ++i) {
    int c = t + i * 256;
    out[c] = f2bf(g[c] * xv[i] * rs);
  }
}

// ---------------- merged Q-GEMM + KV-GEMM: 128x128 tile, BK=64, 4 waves ----------------
__global__ __launch_bounds__(256, 4) void gemm_bt2(const unsigned short* __restrict__ Aq,
                                                   const unsigned short* __restrict__ Bq,
                                                   const unsigned short* __restrict__ Akv,
                                                   const unsigned short* __restrict__ Bkv,
                                                   unsigned short* __restrict__ qout,
                                                   float* __restrict__ kout,
                                                   float* __restrict__ vout,
                                                   unsigned short* __restrict__ kb,
                                                   unsigned short* __restrict__ vt) {
  __shared__ __align__(16) unsigned short sA[128 * 64];
  __shared__ __align__(16) unsigned short sB[128 * 64];
  const int t = threadIdx.x, w = t >> 6, l = t & 63;
  const int l15 = l & 15, lh = l >> 4;
  const int swz7 = l15 & 7;
  const int wm = w >> 1, wn = w & 1;
  const int id = blockIdx.x;
  const int xcd = id & 7, slot = id >> 3;
  const int y = xcd + 8 * (slot >> 3);
  const int mb = slot & 7;
  const bool isQ = y < 192;
  const int nb = isQ ? y : y - 192;
  const int K = isQ ? QLORA : 512;
  const unsigned short* Ab = (isQ ? Aq : Akv) + (long)mb * 128 * K;
  const unsigned short* Bb = (isQ ? Bq : Bkv) + (long)nb * 128 * K;
  f32x4 acc[4][4];
  #pragma unroll
  for (int i = 0; i < 4; ++i)
    #pragma unroll
    for (int j = 0; j < 4; ++j)
      #pragma unroll
      for (int r = 0; r < 4; ++r) acc[i][j][r] = 0.f;

  const int srow = l >> 3;
  const int scol = ((l & 7) ^ srow) * 8;

  for (int kt = 0; kt < K; kt += 64) {
    #pragma unroll
    for (int i = 0; i < 4; ++i) {
      const int chunk = i * 4 + w;
      const int r = chunk * 8 + srow;
      g2l16(Ab + (long)r * K + kt + scol, (char*)sA + chunk * 1024);
      g2l16(Bb + (long)r * K + kt + scol, (char*)sB + chunk * 1024);
    }
    __syncthreads();
    #pragma unroll
    for (int ks = 0; ks < 2; ++ks) {
      bf16x8 af[4], bfr[4];
      #pragma unroll
      for (int i = 0; i < 4; ++i)
        af[i] = *(const bf16x8*)(sA + (wm * 64 + i * 16 + l15) * 64 + ((ks * 4 + lh) ^ swz7) * 8);
      #pragma unroll
      for (int j = 0; j < 4; ++j)
        bfr[j] = *(const bf16x8*)(sB + (wn * 64 + j * 16 + l15) * 64 + ((ks * 4 + lh) ^ swz7) * 8);
      #pragma unroll
      for (int i = 0; i < 4; ++i)
        #pragma unroll
        for (int j = 0; j < 4; ++j)
          acc[i][j] = __builtin_amdgcn_mfma_f32_16x16x32_bf16(af[i], bfr[j], acc[i][j], 0, 0, 0);
    }
    __syncthreads();
  }

  const long rowbase = (long)mb * 128 + wm * 64;
  const long b_ = rowbase >> 9;
  const int colbase = nb * 128 + wn * 64;
  #pragma unroll
  for (int i = 0; i < 4; ++i) {
    const long qi0 = (rowbase + i * 16 + lh * 4) & 511;
    #pragma unroll
    for (int j = 0; j < 4; ++j) {
      const int col = colbase + j * 16 + l15;
      if (isQ) {
        const int h = col / QHD, d = col - h * QHD;
        unsigned short* qp = qout + ((b_ * NHEAD + h) * QLEN + qi0) * QHD + d;
        #pragma unroll
        for (int r4 = 0; r4 < 4; ++r4) qp[(long)r4 * QHD] = f2bf(acc[i][j][r4]);
      } else {
        const int h = col >> 8, d = col & 255;
        if (d < 128) {
          const long idx = ((b_ * NHEAD + h) * KVTOT + 512 + qi0) * QHD + d;
          #pragma unroll
          for (int r4 = 0; r4 < 4; ++r4) {
            kout[idx + (long)r4 * QHD] = acc[i][j][r4];
            kb[idx + (long)r4 * QHD] = f2bf(acc[i][j][r4]);
          }
        } else {
          const int dv = d - 128;
          float* vp = vout + ((b_ * NHEAD + h) * KVTOT + 512 + qi0) * VHD + dv;
          u16x4 tv;
          #pragma unroll
          for (int r4 = 0; r4 < 4; ++r4) {
            vp[(long)r4 * VHD] = acc[i][j][r4];
            tv[r4] = f2bf(acc[i][j][r4]);
          }
          *(u16x4*)(vt + ((b_ * NHEAD + h) * VHD + dv) * KVTOT + 512 + qi0) = tv;
        }
      }
    }
  }
}

// ---------------- attention staging helpers (XOR-swizzled source, linear LDS dest) ----
static __device__ __forceinline__ void stage_k_tile(const unsigned short* __restrict__ src,
                                                    char* dstbase, int t) {
  const int w = t >> 6;
  #pragma unroll
  for (int i2 = 0; i2 < 6; ++i2) {
    int n = i2 * 256 + t;
    int r = n / 24, cp = n - r * 24;
    int c = cp ^ (r & 7);
    g2l16(src + (long)r * QHD + c * 8, dstbase + (i2 * 256 + w * 64) * 16);
  }
}

static __device__ __forceinline__ void stage_v_tile(const unsigned short* __restrict__ src,
                                                    char* dstbase, int t) {
  const int w = t >> 6;
  #pragma unroll
  for (int i2 = 0; i2 < 4; ++i2) {
    int n = i2 * 256 + t;
    int r = n >> 3, cp = n & 7;
    int c = cp ^ (r & 7);
    g2l16(src + (long)r * KVTOT + c * 8, dstbase + (i2 * 256 + w * 64) * 16);
  }
}

// ---------------- flash attention: 1 block = (b,h, 128-row q tile), 4 waves ------------
// 40 KB single-K-buffer structure, launch_bounds(256,2) (128 VGPR, no spill).
__global__ __launch_bounds__(256, 2) void attn_k(const unsigned short* __restrict__ Qw,
                                                 const unsigned short* __restrict__ Kb,
                                                 const unsigned short* __restrict__ Vt,
                                                 const float* __restrict__ mask,
                                                 const int* __restrict__ flags,
                                                 float* __restrict__ outp) {
  __shared__ __align__(16) unsigned short sK[64 * 192];   // 24 KB; doubles as sP after QK
  __shared__ __align__(16) unsigned short sV[128 * 64];   // 16 KB
  const int t = threadIdx.x, w = t >> 6, l = t & 63;
  const int l15 = l & 15, lh = l >> 4;
  const int raw = blockIdx.x;
  const int xcd = raw & 7, slot = raw >> 3;
  const int bh = xcd * 32 + (slot >> 2), qt = slot & 3;
  const long b_ = bh >> 7;
  const float SCALE = 0.051023330039633184f;
  const int swz = l15 & 7;

  bf16x8 qf[2][6];
  const unsigned short* Qb = Qw + ((long)bh * QLEN + qt * 128 + w * 32) * QHD;
  #pragma unroll
  for (int i = 0; i < 2; ++i)
    #pragma unroll
    for (int ks = 0; ks < 6; ++ks)
      qf[i][ks] = *(const bf16x8*)(Qb + (i * 16 + l15) * QHD + ks * 32 + lh * 8);

  f32x4 o[2][8];
  #pragma unroll
  for (int i = 0; i < 2; ++i)
    #pragma unroll
    for (int j = 0; j < 8; ++j)
      #pragma unroll
      for (int r = 0; r < 4; ++r) o[i][j][r] = 0.f;
  float m_[2][4], l_[2][4];
  #pragma unroll
  for (int i = 0; i < 2; ++i)
    #pragma unroll
    for (int r = 0; r < 4; ++r) { m_[i][r] = -1e30f; l_[i][r] = 0.f; }

  const int qrow0 = qt * 128 + w * 32;
  const unsigned short* Kbh = Kb + (long)bh * KVTOT * QHD;
  const unsigned short* Vbh = Vt + (long)bh * VHD * KVTOT;
  const float* mrow = mask + b_ * 524288 + (long)(qrow0 + lh * 4) * 1024 + l15;
  const int fbase = (int)b_ * 64 + qt * 16;

  for (int kt = 0; kt < 16; ++kt) {
    stage_k_tile(Kbh + (long)kt * 64 * QHD, (char*)sK, t);
    stage_v_tile(Vbh + kt * 64, (char*)sV, t);
    const int flag = flags[fbase + kt];
    __syncthreads();  // B: staging drained

    f32x4 s[2][4];
    #pragma unroll
    for (int i = 0; i < 2; ++i)
      #pragma unroll
      for (int j = 0; j < 4; ++j)
        #pragma unroll
        for (int r = 0; r < 4; ++r) s[i][j][r] = 0.f;
    __builtin_amdgcn_s_setprio(1);
    #pragma unroll
    for (int j = 0; j < 4; ++j) {
      #pragma unroll
      for (int ks = 0; ks < 6; ++ks) {
        bf16x8 kf = *(const bf16x8*)(sK + ((j * 16 + l15) * 24 + ((ks * 4 + lh) ^ swz)) * 8);
        s[0][j] = __builtin_amdgcn_mfma_f32_16x16x32_bf16(qf[0][ks], kf, s[0][j], 0, 0, 0);
        s[1][j] = __builtin_amdgcn_mfma_f32_16x16x32_bf16(qf[1][ks], kf, s[1][j], 0, 0, 0);
      }
    }
    __builtin_amdgcn_s_setprio(0);

    unsigned short pk16[2][4][4];
    #pragma unroll
    for (int i = 0; i < 2; ++i) {
      #pragma unroll
      for (int rg = 0; rg < 4; ++rg) {
        float sc[4];
        if (flag) {
          #pragma unroll
          for (int j = 0; j < 4; ++j)
            sc[j] = s[i][j][rg] * SCALE + mrow[(long)(i * 16 + rg) * 1024 + kt * 64 + j * 16];
        } else {
          #pragma unroll
          for (int j = 0; j < 4; ++j) sc[j] = s[i][j][rg] * SCALE;
        }
        float mx = fmaxf(fmaxf(sc[0], sc[1]), fmaxf(sc[2], sc[3]));
        mx = fmaxf(mx, __shfl_xor(mx, 1));
        mx = fmaxf(mx, __shfl_xor(mx, 2));
        mx = fmaxf(mx, __shfl_xor(mx, 4));
        mx = fmaxf(mx, __shfl_xor(mx, 8));
        float mo = m_[i][rg];
        float mn = fmaxf(mo, mx);
        if (__any(mn > mo)) {
          float al = __expf(mo - mn);
          #pragma unroll
          for (int jj = 0; jj < 8; ++jj) o[i][jj][rg] *= al;
          l_[i][rg] *= al;
          m_[i][rg] = mn;
        }
        float ps = 0.f;
        #pragma unroll
        for (int j = 0; j < 4; ++j) {
          float p = __expf(sc[j] - m_[i][rg]);
          ps += p;
          pk16[i][rg][j] = f2bf(p);
        }
        l_[i][rg] += ps;
      }
    }
    __syncthreads();  // C: QK^T reads done -> sK reusable as sP

    unsigned short* sPc = (unsigned short*)sK;
    #pragma unroll
    for (int i = 0; i < 2; ++i)
      #pragma unroll
      for (int rg = 0; rg < 4; ++rg) {
        const int prow = w * 32 + i * 16 + lh * 4 + rg;
        #pragma unroll
        for (int j = 0; j < 4; ++j)
          sPc[prow * 72 + j * 16 + l15] = pk16[i][rg][j];
      }

    __builtin_amdgcn_s_setprio(1);
    #pragma unroll
    for (int ks = 0; ks < 2; ++ks) {
      bf16x8 pf0 = *(const bf16x8*)(sPc + (w * 32 + l15) * 72 + ks * 32 + lh * 8);
      bf16x8 pf1 = *(const bf16x8*)(sPc + (w * 32 + 16 + l15) * 72 + ks * 32 + lh * 8);
      #pragma unroll
      for (int jj = 0; jj < 8; ++jj) {
        bf16x8 vf = *(const bf16x8*)(sV + ((jj * 16 + l15) * 8 + ((ks * 4 + lh) ^ swz)) * 8);
        o[0][jj] = __builtin_amdgcn_mfma_f32_16x16x32_bf16(pf0, vf, o[0][jj], 0, 0, 0);
        o[1][jj] = __builtin_amdgcn_mfma_f32_16x16x32_bf16(pf1, vf, o[1][jj], 0, 0, 0);
      }
    }
    __builtin_amdgcn_s_setprio(0);
    __syncthreads();  // A: PV reads done before next iter's staging
  }

  #pragma unroll
  for (int i = 0; i < 2; ++i) {
    #pragma unroll
    for (int rg = 0; rg < 4; ++rg) {
      float ls = l_[i][rg];
      ls += __shfl_xor(ls, 1);
      ls += __shfl_xor(ls, 2);
      ls += __shfl_xor(ls, 4);
      ls += __shfl_xor(ls, 8);
      float inv = 1.0f / ls;
      long row = (long)bh * QLEN + qrow0 + i * 16 + lh * 4 + rg;
      #pragma unroll
      for (int jj = 0; jj < 8; ++jj)
        outp[row * VHD + jj * 16 + l15] = o[i][jj][rg] * inv;
    }
  }
}

// ---------------- workspace layout (bytes) ----------------
#define WS_HID_BF   0L
#define WS_WQA_BF   10485760L
#define WS_WQB_BF   32768000L
#define WS_WKVB_BF  108265472L
#define WS_QAN_BF   141819904L
#define WS_CKVN_BF  144965632L
#define WS_Q_BF     146014208L   // part f32 (2x1024x2176x4 = 17.8MB) aliased here first
#define WS_KB_BF    196345856L
#define WS_VT_BF    297009152L
#define WS_FLAGS    364118016L

extern "C" void kernel_launch(void* const* d_in, const int* in_sizes, int n_in,
                              void* d_out, int out_size, void* d_ws, size_t ws_size,
                              hipStream_t stream) {
  const float* hs   = (const float*)d_in[0];
  const float* mask = (const float*)d_in[1];
  const float* pk   = (const float*)d_in[2];
  const float* pv   = (const float*)d_in[3];
  const float* wqa  = (const float*)d_in[4];
  const float* gqa  = (const float*)d_in[5];
  const float* wqb  = (const float*)d_in[6];
  const float* wkva = (const float*)d_in[7];
  const float* gkva = (const float*)d_in[8];
  const float* wkvb = (const float*)d_in[9];

  char* ws = (char*)d_ws;
  unsigned short* hid_bf  = (unsigned short*)(ws + WS_HID_BF);
  unsigned short* wqa_bf  = (unsigned short*)(ws + WS_WQA_BF);
  unsigned short* wkva_bf = wqa_bf + (long)1536 * 5120;
  unsigned short* wpad_bf = wqa_bf + (long)2112 * 5120;
  unsigned short* wqb_bf  = (unsigned short*)(ws + WS_WQB_BF);
  unsigned short* wkvb_bf = (unsigned short*)(ws + WS_WKVB_BF);
  unsigned short* qan_bf  = (unsigned short*)(ws + WS_QAN_BF);
  unsigned short* ckvn_bf = (unsigned short*)(ws + WS_CKVN_BF);
  unsigned short* q_bf    = (unsigned short*)(ws + WS_Q_BF);
  float*          part    = (float*)(ws + WS_Q_BF);
  unsigned short* kb_bf   = (unsigned short*)(ws + WS_KB_BF);
  unsigned short* vt_bf   = (unsigned short*)(ws + WS_VT_BF);
  int*            flags   = (int*)(ws + WS_FLAGS);

  float* out_attn = (float*)d_out;
  float* out_key  = (float*)d_out + 16777216;
  float* out_val  = (float*)d_out + 67108864;

  // 1. prep: cvt(hs,wqa,wkva) + mask flags + pad zero
  prep_k<<<4208, 256, 0, stream>>>(hs, hid_bf, wqa, wqa_bf, wkva, wkva_bf,
                                   mask, flags, wpad_bf);
  // 2. MEGA: qa_ckv GEMM (ids 0-575, compute) co-scheduled with cvt(wqb,wkvb) +
  //    past-key copy + V past copy/transpose (pure BW) -> max(compute, BW) not sum
  mega1_k<<<40512, 256, 0, stream>>>(hid_bf, wqa_bf, part,
                                     wqb, wqb_bf, wkvb, wkvb_bf,
                                     pk, out_key, kb_bf,
                                     pv, out_val, vt_bf);
  // 3. rmsnorms + k_pe broadcast
  post_a_k<<<3072, 256, 0, stream>>>(part, gqa, gkva, qan_bf, ckvn_bf, out_key, kb_bf);
  // 4. merged Q-GEMM + KV-GEMM
  gemm_bt2<<<3584, 256, 0, stream>>>(qan_bf, wqb_bf, ckvn_bf, wkvb_bf,
                                     q_bf, out_key, out_val, kb_bf, vt_bf);
  // 5. attention
  attn_k<<<1024, 256, 0, stream>>>(q_bf, kb_bf, vt_bf, mask, flags, out_attn);
}

// Round 14
// 528.615 us; speedup vs baseline: 2.0940x; 1.0165x over previous
//
#include <hip/hip_runtime.h>

// ---------------- problem constants ----------------
#define NB    2
#define QLEN  512
#define HIDD  5120
#define QLORA 1536
#define NHEAD 128
#define QHD   192
#define VHD   128
#define KVTOT 1024

typedef float          f32x4   __attribute__((ext_vector_type(4)));
typedef __bf16         bf16x8  __attribute__((ext_vector_type(8)));
typedef unsigned short u16x8   __attribute__((ext_vector_type(8)));
typedef unsigned short u16x4   __attribute__((ext_vector_type(4)));

static __device__ __forceinline__ unsigned short f2bf(float f) {
  union { float f; unsigned u; } v; v.f = f;
  return (unsigned short)((v.u + 0x7fffu + ((v.u >> 16) & 1u)) >> 16);
}

static __device__ __forceinline__ void g2l16(const void* g, void* l) {
  __builtin_amdgcn_global_load_lds(
      (const __attribute__((address_space(1))) void*)g,
      (__attribute__((address_space(3))) void*)l, 16, 0, 0);
}

// ---------------- prep kernel: cvt(hs,wqa,wkva) + mask flags + pad-zero ----------------
// ids [0,1280) hs | [1280,3200) wqa | [3200,3920) wkva | [3920,4048) flags | [4048,4208) pad
__global__ __launch_bounds__(256) void prep_k(const float* __restrict__ hs,
                                              unsigned short* __restrict__ hid,
                                              const float* __restrict__ wqa,
                                              unsigned short* __restrict__ wqaB,
                                              const float* __restrict__ wkva,
                                              unsigned short* __restrict__ wkvaB,
                                              const float* __restrict__ mask,
                                              int* __restrict__ flags,
                                              unsigned short* __restrict__ pad) {
  __shared__ int sf[4];
  const int gid = blockIdx.x, t = threadIdx.x;
  if (gid < 3920) {
    const float* in; unsigned short* out; long lb;
    if (gid < 1280)      { in = hs;   out = hid;   lb = gid; }
    else if (gid < 3200) { in = wqa;  out = wqaB;  lb = gid - 1280; }
    else                 { in = wkva; out = wkvaB; lb = gid - 3200; }
    long base = lb * 1024 + t;
    #pragma unroll
    for (int k = 0; k < 4; ++k) {
      long i = base + k * 256;
      f32x4 v = *(const f32x4*)(in + i * 4);
      u16x4 o;
      o[0] = f2bf(v[0]); o[1] = f2bf(v[1]); o[2] = f2bf(v[2]); o[3] = f2bf(v[3]);
      *(u16x4*)(out + i * 4) = o;
    }
  } else if (gid < 4048) {
    int id = gid - 3920;  // b*64 + qt*16 + kt
    int b = id >> 6, qt = (id >> 4) & 3, kt = id & 15;
    const float* base = mask + (long)b * 524288 + (long)qt * 128 * 1024 + kt * 64;
    int w = t >> 6;
    unsigned acc = 0;
    #pragma unroll
    for (int i = 0; i < 32; ++i) {
      int e = i * 256 + t;
      int r = e >> 6, c = e & 63;
      union { float f; unsigned u; } v; v.f = base[(long)r * 1024 + c];
      acc |= v.u;
    }
    int any = __any(acc != 0);
    if ((t & 63) == 0) sf[w] = any;
    __syncthreads();
    if (t == 0) flags[id] = sf[0] | sf[1] | sf[2] | sf[3];
  } else {
    int i = (gid - 4048) * 256 + t;
    u16x8 z = {0, 0, 0, 0, 0, 0, 0, 0};
    *(u16x8*)(pad + (long)i * 8) = z;
  }
}

// ---------------- MEGA kernel 1: qa_ckv GEMM + cvt(wqb,wkvb) + copy_key + vfix ----------
__global__ __launch_bounds__(256, 4) void mega1_k(
    const unsigned short* __restrict__ A, const unsigned short* __restrict__ Bm,
    float* __restrict__ part,
    const float* __restrict__ wqbF, unsigned short* __restrict__ wqbB,
    const float* __restrict__ wkvbF, unsigned short* __restrict__ wkvbB,
    const float* __restrict__ pk, float* __restrict__ kout, unsigned short* __restrict__ kb,
    const float* __restrict__ pv, float* __restrict__ outv, unsigned short* __restrict__ vt) {
  __shared__ __align__(16) char smem[24576];
  const int gid = blockIdx.x, t = threadIdx.x;

  if (gid < 576) {
    unsigned short* sA = (unsigned short*)smem;
    unsigned short* sB = (unsigned short*)(smem + 16384);
    const int w = t >> 6, l = t & 63;
    const int l15 = l & 15, lh = l >> 4;
    const int swz7 = l15 & 7;
    const int xcd = gid & 7, slot = gid >> 3;
    const int pz = xcd + 8 * (slot >> 3);
    const int mb = slot & 7;
    if (pz >= 68) return;
    const int z = (pz >= 34) ? 1 : 0;
    const int nb = pz - z * 34;
    const unsigned short* Ab = A + (long)mb * 128 * HIDD;
    const unsigned short* Bb = Bm + (long)nb * 64 * HIDD;
    f32x4 acc[2][4];
    #pragma unroll
    for (int i = 0; i < 2; ++i)
      #pragma unroll
      for (int j = 0; j < 4; ++j)
        #pragma unroll
        for (int r = 0; r < 4; ++r) acc[i][j][r] = 0.f;

    const int k0 = z * 2560;
    for (int kt = k0; kt < k0 + 2560; kt += 64) {
      #pragma unroll
      for (int i2 = 0; i2 < 4; ++i2) {
        int n = i2 * 256 + t, r = n >> 3, c = (n & 7) ^ (r & 7);
        g2l16(Ab + (long)r * HIDD + kt + c * 8, (char*)sA + (i2 * 256 + w * 64) * 16);
      }
      #pragma unroll
      for (int i2 = 0; i2 < 2; ++i2) {
        int n = i2 * 256 + t, r = n >> 3, c = (n & 7) ^ (r & 7);
        g2l16(Bb + (long)r * HIDD + kt + c * 8, (char*)sB + (i2 * 256 + w * 64) * 16);
      }
      __syncthreads();
      #pragma unroll
      for (int ks = 0; ks < 2; ++ks) {
        bf16x8 af[2], bfr[4];
        #pragma unroll
        for (int i = 0; i < 2; ++i)
          af[i] = *(const bf16x8*)(sA + (w * 32 + i * 16 + l15) * 64 + ((ks * 4 + lh) ^ swz7) * 8);
        #pragma unroll
        for (int j = 0; j < 4; ++j)
          bfr[j] = *(const bf16x8*)(sB + (j * 16 + l15) * 64 + ((ks * 4 + lh) ^ swz7) * 8);
        #pragma unroll
        for (int i = 0; i < 2; ++i)
          #pragma unroll
          for (int j = 0; j < 4; ++j)
            acc[i][j] = __builtin_amdgcn_mfma_f32_16x16x32_bf16(af[i], bfr[j], acc[i][j], 0, 0, 0);
      }
      __syncthreads();
    }
    float* po = part + (long)z * 1024 * 2176;
    const int colbase = nb * 64;
    #pragma unroll
    for (int i = 0; i < 2; ++i)
      #pragma unroll
      for (int j = 0; j < 4; ++j) {
        const int col = colbase + j * 16 + l15;
        #pragma unroll
        for (int r4 = 0; r4 < 4; ++r4) {
          const long row = (long)mb * 128 + w * 32 + i * 16 + lh * 4 + r4;
          po[row * 2176 + col] = acc[i][j][r4];
        }
      }
  } else if (gid < 13888) {
    long lb = gid - 576;
    const float* in; unsigned short* out;
    if (lb < 9216) { in = wqbF; out = wqbB; }
    else           { in = wkvbF; out = wkvbB; lb -= 9216; }
    long base = lb * 1024 + t;
    #pragma unroll
    for (int k = 0; k < 4; ++k) {
      long i = base + k * 256;
      f32x4 v = *(const f32x4*)(in + i * 4);
      u16x4 o;
      o[0] = f2bf(v[0]); o[1] = f2bf(v[1]); o[2] = f2bf(v[2]); o[3] = f2bf(v[3]);
      *(u16x4*)(out + i * 4) = o;
    }
  } else if (gid < 38464) {
    long i4 = (long)(gid - 13888) * 256 + t;
    f32x4 v = *(const f32x4*)(pk + i4 * 4);
    long e = i4 * 4;
    long bh = e / 98304;
    long rem = e - bh * 98304;
    long oidx = bh * 196608 + rem;
    *(f32x4*)(kout + oidx) = v;
    u16x4 b;
    b[0] = f2bf(v[0]); b[1] = f2bf(v[1]); b[2] = f2bf(v[2]); b[3] = f2bf(v[3]);
    *(u16x4*)(kb + oidx) = b;
  } else {
    unsigned short* sT = (unsigned short*)smem;
    int lid = gid - 38464;
    int bh = lid >> 3, kt = lid & 7;
    const float* src = pv + ((long)bh * 512 + kt * 64) * VHD;
    float* dstv = outv + ((long)bh * KVTOT + kt * 64) * VHD;
    #pragma unroll
    for (int i = 0; i < 8; ++i) {
      int id = t + i * 256;
      int r = id >> 5, c4 = (id & 31) * 4;
      f32x4 v = *(const f32x4*)(src + (long)r * VHD + c4);
      *(f32x4*)(dstv + (long)r * VHD + c4) = v;
      #pragma unroll
      for (int jj = 0; jj < 4; ++jj) sT[(c4 + jj) * 72 + r] = f2bf(v[jj]);
    }
    __syncthreads();
    #pragma unroll
    for (int i = 0; i < 4; ++i) {
      int id = t + i * 256;
      int d = id >> 3, c = id & 7;
      u16x8 v = *(const u16x8*)(sT + d * 72 + c * 8);
      *(u16x8*)(vt + ((long)bh * VHD + d) * KVTOT + kt * 64 + c * 8) = v;
    }
  }
}

// ---------------- fused rmsnorm(q_a) + rmsnorm(ckv) + k_pe broadcast (2 partials) ------
__global__ __launch_bounds__(256) void post_a_k(const float* __restrict__ part,
                                                const float* __restrict__ gq,
                                                const float* __restrict__ gkv,
                                                unsigned short* __restrict__ qan,
                                                unsigned short* __restrict__ ckvn,
                                                float* __restrict__ kout,
                                                unsigned short* __restrict__ kb) {
  const long ZS = 1024L * 2176;
  int bid = blockIdx.x, t = threadIdx.x;
  if (bid >= 2048) {  // k_pe broadcast
    int row = bid - 2048;
    int j = t & 63, h0 = t >> 6;
    const float* p = part + (long)row * 2176 + 2048 + j;
    float v = p[0] + p[ZS];
    unsigned short vb = f2bf(v);
    long b_ = row >> 9, qi = row & 511;
    for (int h = h0; h < NHEAD; h += 4) {
      long idx = ((b_ * NHEAD + h) * KVTOT + 512 + qi) * QHD + 128 + j;
      kout[idx] = v;
      kb[idx] = vb;
    }
    return;
  }
  bool isQ = bid < 1024;
  int row = isQ ? bid : bid - 1024;
  int cols = isQ ? 1536 : 512;
  const float* g = isQ ? gq : gkv;
  unsigned short* out = isQ ? (qan + (long)row * 1536) : (ckvn + (long)row * 512);
  const float* x = part + (long)row * 2176 + (isQ ? 0 : 1536);
  int w = t >> 6, l = t & 63;
  float xv[6];
  int nc = cols >> 8;
  float ss = 0.f;
  for (int i = 0; i < nc; ++i) {
    int c = t + i * 256;
    float v = x[c] + x[c + ZS];
    xv[i] = v; ss += v * v;
  }
  #pragma unroll
  for (int m = 32; m >= 1; m >>= 1) ss += __shfl_xor(ss, m);
  __shared__ float red[4];
  if (l == 0) red[w] = ss;
  __syncthreads();
  float tot = red[0] + red[1] + red[2] + red[3];
  float rs = rsqrtf(tot / (float)cols + 1e-6f);
  for (int i = 0; i < nc; ++i) {
    int c = t + i * 256;
    out[c] = f2bf(g[c] * xv[i] * rs);
  }
}

// ---------------- merged Q-GEMM + KV-GEMM: 128x128 tile, BK=64, 4 waves ----------------
__global__ __launch_bounds__(256, 4) void gemm_bt2(const unsigned short* __restrict__ Aq,
                                                   const unsigned short* __restrict__ Bq,
                                                   const unsigned short* __restrict__ Akv,
                                                   const unsigned short* __restrict__ Bkv,
                                                   unsigned short* __restrict__ qout,
                                                   float* __restrict__ kout,
                                                   float* __restrict__ vout,
                                                   unsigned short* __restrict__ kb,
                                                   unsigned short* __restrict__ vt) {
  __shared__ __align__(16) unsigned short sA[128 * 64];
  __shared__ __align__(16) unsigned short sB[128 * 64];
  const int t = threadIdx.x, w = t >> 6, l = t & 63;
  const int l15 = l & 15, lh = l >> 4;
  const int swz7 = l15 & 7;
  const int wm = w >> 1, wn = w & 1;
  const int id = blockIdx.x;
  const int xcd = id & 7, slot = id >> 3;
  const int y = xcd + 8 * (slot >> 3);
  const int mb = slot & 7;
  const bool isQ = y < 192;
  const int nb = isQ ? y : y - 192;
  const int K = isQ ? QLORA : 512;
  const unsigned short* Ab = (isQ ? Aq : Akv) + (long)mb * 128 * K;
  const unsigned short* Bb = (isQ ? Bq : Bkv) + (long)nb * 128 * K;
  f32x4 acc[4][4];
  #pragma unroll
  for (int i = 0; i < 4; ++i)
    #pragma unroll
    for (int j = 0; j < 4; ++j)
      #pragma unroll
      for (int r = 0; r < 4; ++r) acc[i][j][r] = 0.f;

  const int srow = l >> 3;
  const int scol = ((l & 7) ^ srow) * 8;

  for (int kt = 0; kt < K; kt += 64) {
    #pragma unroll
    for (int i = 0; i < 4; ++i) {
      const int chunk = i * 4 + w;
      const int r = chunk * 8 + srow;
      g2l16(Ab + (long)r * K + kt + scol, (char*)sA + chunk * 1024);
      g2l16(Bb + (long)r * K + kt + scol, (char*)sB + chunk * 1024);
    }
    __syncthreads();
    #pragma unroll
    for (int ks = 0; ks < 2; ++ks) {
      bf16x8 af[4], bfr[4];
      #pragma unroll
      for (int i = 0; i < 4; ++i)
        af[i] = *(const bf16x8*)(sA + (wm * 64 + i * 16 + l15) * 64 + ((ks * 4 + lh) ^ swz7) * 8);
      #pragma unroll
      for (int j = 0; j < 4; ++j)
        bfr[j] = *(const bf16x8*)(sB + (wn * 64 + j * 16 + l15) * 64 + ((ks * 4 + lh) ^ swz7) * 8);
      #pragma unroll
      for (int i = 0; i < 4; ++i)
        #pragma unroll
        for (int j = 0; j < 4; ++j)
          acc[i][j] = __builtin_amdgcn_mfma_f32_16x16x32_bf16(af[i], bfr[j], acc[i][j], 0, 0, 0);
    }
    __syncthreads();
  }

  const long rowbase = (long)mb * 128 + wm * 64;
  const long b_ = rowbase >> 9;
  const int colbase = nb * 128 + wn * 64;
  #pragma unroll
  for (int i = 0; i < 4; ++i) {
    const long qi0 = (rowbase + i * 16 + lh * 4) & 511;
    #pragma unroll
    for (int j = 0; j < 4; ++j) {
      const int col = colbase + j * 16 + l15;
      if (isQ) {
        const int h = col / QHD, d = col - h * QHD;
        unsigned short* qp = qout + ((b_ * NHEAD + h) * QLEN + qi0) * QHD + d;
        #pragma unroll
        for (int r4 = 0; r4 < 4; ++r4) qp[(long)r4 * QHD] = f2bf(acc[i][j][r4]);
      } else {
        const int h = col >> 8, d = col & 255;
        if (d < 128) {
          const long idx = ((b_ * NHEAD + h) * KVTOT + 512 + qi0) * QHD + d;
          #pragma unroll
          for (int r4 = 0; r4 < 4; ++r4) {
            kout[idx + (long)r4 * QHD] = acc[i][j][r4];
            kb[idx + (long)r4 * QHD] = f2bf(acc[i][j][r4]);
          }
        } else {
          const int dv = d - 128;
          float* vp = vout + ((b_ * NHEAD + h) * KVTOT + 512 + qi0) * VHD + dv;
          u16x4 tv;
          #pragma unroll
          for (int r4 = 0; r4 < 4; ++r4) {
            vp[(long)r4 * VHD] = acc[i][j][r4];
            tv[r4] = f2bf(acc[i][j][r4]);
          }
          *(u16x4*)(vt + ((b_ * NHEAD + h) * VHD + dv) * KVTOT + 512 + qi0) = tv;
        }
      }
    }
  }
}

// ---------------- attention staging helpers (XOR-swizzled source, linear LDS dest) ----
static __device__ __forceinline__ void stage_k_tile(const unsigned short* __restrict__ src,
                                                    char* dstbase, int t) {
  const int w = t >> 6;
  #pragma unroll
  for (int i2 = 0; i2 < 6; ++i2) {
    int n = i2 * 256 + t;
    int r = n / 24, cp = n - r * 24;
    int c = cp ^ (r & 7);
    g2l16(src + (long)r * QHD + c * 8, dstbase + (i2 * 256 + w * 64) * 16);
  }
}

static __device__ __forceinline__ void stage_v_tile(const unsigned short* __restrict__ src,
                                                    char* dstbase, int t) {
  const int w = t >> 6;
  #pragma unroll
  for (int i2 = 0; i2 < 4; ++i2) {
    int n = i2 * 256 + t;
    int r = n >> 3, cp = n & 7;
    int c = cp ^ (r & 7);
    g2l16(src + (long)r * KVTOT + c * 8, dstbase + (i2 * 256 + w * 64) * 16);
  }
}

// ---------------- flash attention: 1 block = (b,h, 128-row q tile), 4 waves ------------
// 40 KB single-K-buffer; launch_bounds(256,2). Softmax in LOG2 domain (exp2 native),
// T13 defer-max THR=8 (P<=256, bf16 headroom fine), cvt_pk bf16 packing.
__global__ __launch_bounds__(256, 2) void attn_k(const unsigned short* __restrict__ Qw,
                                                 const unsigned short* __restrict__ Kb,
                                                 const unsigned short* __restrict__ Vt,
                                                 const float* __restrict__ mask,
                                                 const int* __restrict__ flags,
                                                 float* __restrict__ outp) {
  __shared__ __align__(16) unsigned short sK[64 * 192];   // 24 KB; doubles as sP after QK
  __shared__ __align__(16) unsigned short sV[128 * 64];   // 16 KB
  const int t = threadIdx.x, w = t >> 6, l = t & 63;
  const int l15 = l & 15, lh = l >> 4;
  const int raw = blockIdx.x;
  const int xcd = raw & 7, slot = raw >> 3;
  const int bh = xcd * 32 + (slot >> 2), qt = slot & 3;
  const long b_ = bh >> 7;
  // log2-domain scale: SCALE * log2(e)
  const float SCALE_L2E = 0.051023330039633184f * 1.4426950408889634f;
  const float L2E = 1.4426950408889634f;
  const int swz = l15 & 7;

  bf16x8 qf[2][6];
  const unsigned short* Qb = Qw + ((long)bh * QLEN + qt * 128 + w * 32) * QHD;
  #pragma unroll
  for (int i = 0; i < 2; ++i)
    #pragma unroll
    for (int ks = 0; ks < 6; ++ks)
      qf[i][ks] = *(const bf16x8*)(Qb + (i * 16 + l15) * QHD + ks * 32 + lh * 8);

  f32x4 o[2][8];
  #pragma unroll
  for (int i = 0; i < 2; ++i)
    #pragma unroll
    for (int j = 0; j < 8; ++j)
      #pragma unroll
      for (int r = 0; r < 4; ++r) o[i][j][r] = 0.f;
  float m_[2][4], l_[2][4];  // m_ in log2 units; l_ per-lane partial
  #pragma unroll
  for (int i = 0; i < 2; ++i)
    #pragma unroll
    for (int r = 0; r < 4; ++r) { m_[i][r] = -1e30f; l_[i][r] = 0.f; }

  const int qrow0 = qt * 128 + w * 32;
  const unsigned short* Kbh = Kb + (long)bh * KVTOT * QHD;
  const unsigned short* Vbh = Vt + (long)bh * VHD * KVTOT;
  const float* mrow = mask + b_ * 524288 + (long)(qrow0 + lh * 4) * 1024 + l15;
  const int fbase = (int)b_ * 64 + qt * 16;

  for (int kt = 0; kt < 16; ++kt) {
    stage_k_tile(Kbh + (long)kt * 64 * QHD, (char*)sK, t);
    stage_v_tile(Vbh + kt * 64, (char*)sV, t);
    const int flag = flags[fbase + kt];
    __syncthreads();  // B: staging drained

    f32x4 s[2][4];
    #pragma unroll
    for (int i = 0; i < 2; ++i)
      #pragma unroll
      for (int j = 0; j < 4; ++j)
        #pragma unroll
        for (int r = 0; r < 4; ++r) s[i][j][r] = 0.f;
    __builtin_amdgcn_s_setprio(1);
    #pragma unroll
    for (int j = 0; j < 4; ++j) {
      #pragma unroll
      for (int ks = 0; ks < 6; ++ks) {
        bf16x8 kf = *(const bf16x8*)(sK + ((j * 16 + l15) * 24 + ((ks * 4 + lh) ^ swz)) * 8);
        s[0][j] = __builtin_amdgcn_mfma_f32_16x16x32_bf16(qf[0][ks], kf, s[0][j], 0, 0, 0);
        s[1][j] = __builtin_amdgcn_mfma_f32_16x16x32_bf16(qf[1][ks], kf, s[1][j], 0, 0, 0);
      }
    }
    __builtin_amdgcn_s_setprio(0);

    // online softmax (log2 domain, defer-max THR=8)
    unsigned pkw[2][4][2];  // packed bf16 pairs per rowgroup
    #pragma unroll
    for (int i = 0; i < 2; ++i) {
      #pragma unroll
      for (int rg = 0; rg < 4; ++rg) {
        float sc[4];
        if (flag) {
          #pragma unroll
          for (int j = 0; j < 4; ++j)
            sc[j] = s[i][j][rg] * SCALE_L2E +
                    mrow[(long)(i * 16 + rg) * 1024 + kt * 64 + j * 16] * L2E;
        } else {
          #pragma unroll
          for (int j = 0; j < 4; ++j) sc[j] = s[i][j][rg] * SCALE_L2E;
        }
        float mx = fmaxf(fmaxf(sc[0], sc[1]), fmaxf(sc[2], sc[3]));
        mx = fmaxf(mx, __shfl_xor(mx, 1));
        mx = fmaxf(mx, __shfl_xor(mx, 2));
        mx = fmaxf(mx, __shfl_xor(mx, 4));
        mx = fmaxf(mx, __shfl_xor(mx, 8));
        float mo = m_[i][rg];
        if (__any(mx > mo + 8.f)) {       // T13: only rescale when max grows materially
          float mn = fmaxf(mo, mx);
          float al = __builtin_amdgcn_exp2f(mo - mn);
          #pragma unroll
          for (int jj = 0; jj < 8; ++jj) o[i][jj][rg] *= al;
          l_[i][rg] *= al;
          m_[i][rg] = mn;
        }
        float mcur = m_[i][rg];
        float p0 = __builtin_amdgcn_exp2f(sc[0] - mcur);
        float p1 = __builtin_amdgcn_exp2f(sc[1] - mcur);
        float p2 = __builtin_amdgcn_exp2f(sc[2] - mcur);
        float p3 = __builtin_amdgcn_exp2f(sc[3] - mcur);
        l_[i][rg] += (p0 + p1) + (p2 + p3);
        unsigned r01, r23;
        asm("v_cvt_pk_bf16_f32 %0, %1, %2" : "=v"(r01) : "v"(p0), "v"(p1));
        asm("v_cvt_pk_bf16_f32 %0, %1, %2" : "=v"(r23) : "v"(p2), "v"(p3));
        pkw[i][rg][0] = r01;
        pkw[i][rg][1] = r23;
      }
    }
    __syncthreads();  // C: QK^T reads done -> sK reusable as sP

    unsigned short* sPc = (unsigned short*)sK;
    #pragma unroll
    for (int i = 0; i < 2; ++i)
      #pragma unroll
      for (int rg = 0; rg < 4; ++rg) {
        const int prow = w * 32 + i * 16 + lh * 4 + rg;
        unsigned r01 = pkw[i][rg][0], r23 = pkw[i][rg][1];
        sPc[prow * 72 + 0 * 16 + l15] = (unsigned short)r01;
        sPc[prow * 72 + 1 * 16 + l15] = (unsigned short)(r01 >> 16);
        sPc[prow * 72 + 2 * 16 + l15] = (unsigned short)r23;
        sPc[prow * 72 + 3 * 16 + l15] = (unsigned short)(r23 >> 16);
      }

    __builtin_amdgcn_s_setprio(1);
    #pragma unroll
    for (int ks = 0; ks < 2; ++ks) {
      bf16x8 pf0 = *(const bf16x8*)(sPc + (w * 32 + l15) * 72 + ks * 32 + lh * 8);
      bf16x8 pf1 = *(const bf16x8*)(sPc + (w * 32 + 16 + l15) * 72 + ks * 32 + lh * 8);
      #pragma unroll
      for (int jj = 0; jj < 8; ++jj) {
        bf16x8 vf = *(const bf16x8*)(sV + ((jj * 16 + l15) * 8 + ((ks * 4 + lh) ^ swz)) * 8);
        o[0][jj] = __builtin_amdgcn_mfma_f32_16x16x32_bf16(pf0, vf, o[0][jj], 0, 0, 0);
        o[1][jj] = __builtin_amdgcn_mfma_f32_16x16x32_bf16(pf1, vf, o[1][jj], 0, 0, 0);
      }
    }
    __builtin_amdgcn_s_setprio(0);
    __syncthreads();  // A: PV reads done before next iter's staging
  }

  #pragma unroll
  for (int i = 0; i < 2; ++i) {
    #pragma unroll
    for (int rg = 0; rg < 4; ++rg) {
      float ls = l_[i][rg];
      ls += __shfl_xor(ls, 1);
      ls += __shfl_xor(ls, 2);
      ls += __shfl_xor(ls, 4);
      ls += __shfl_xor(ls, 8);
      float inv = 1.0f / ls;
      long row = (long)bh * QLEN + qrow0 + i * 16 + lh * 4 + rg;
      #pragma unroll
      for (int jj = 0; jj < 8; ++jj)
        outp[row * VHD + jj * 16 + l15] = o[i][jj][rg] * inv;
    }
  }
}

// ---------------- workspace layout (bytes) ----------------
#define WS_HID_BF   0L
#define WS_WQA_BF   10485760L
#define WS_WQB_BF   32768000L
#define WS_WKVB_BF  108265472L
#define WS_QAN_BF   141819904L
#define WS_CKVN_BF  144965632L
#define WS_Q_BF     146014208L   // part f32 (2x1024x2176x4 = 17.8MB) aliased here first
#define WS_KB_BF    196345856L
#define WS_VT_BF    297009152L
#define WS_FLAGS    364118016L

extern "C" void kernel_launch(void* const* d_in, const int* in_sizes, int n_in,
                              void* d_out, int out_size, void* d_ws, size_t ws_size,
                              hipStream_t stream) {
  const float* hs   = (const float*)d_in[0];
  const float* mask = (const float*)d_in[1];
  const float* pk   = (const float*)d_in[2];
  const float* pv   = (const float*)d_in[3];
  const float* wqa  = (const float*)d_in[4];
  const float* gqa  = (const float*)d_in[5];
  const float* wqb  = (const float*)d_in[6];
  const float* wkva = (const float*)d_in[7];
  const float* gkva = (const float*)d_in[8];
  const float* wkvb = (const float*)d_in[9];

  char* ws = (char*)d_ws;
  unsigned short* hid_bf  = (unsigned short*)(ws + WS_HID_BF);
  unsigned short* wqa_bf  = (unsigned short*)(ws + WS_WQA_BF);
  unsigned short* wkva_bf = wqa_bf + (long)1536 * 5120;
  unsigned short* wpad_bf = wqa_bf + (long)2112 * 5120;
  unsigned short* wqb_bf  = (unsigned short*)(ws + WS_WQB_BF);
  unsigned short* wkvb_bf = (unsigned short*)(ws + WS_WKVB_BF);
  unsigned short* qan_bf  = (unsigned short*)(ws + WS_QAN_BF);
  unsigned short* ckvn_bf = (unsigned short*)(ws + WS_CKVN_BF);
  unsigned short* q_bf    = (unsigned short*)(ws + WS_Q_BF);
  float*          part    = (float*)(ws + WS_Q_BF);
  unsigned short* kb_bf   = (unsigned short*)(ws + WS_KB_BF);
  unsigned short* vt_bf   = (unsigned short*)(ws + WS_VT_BF);
  int*            flags   = (int*)(ws + WS_FLAGS);

  float* out_attn = (float*)d_out;
  float* out_key  = (float*)d_out + 16777216;
  float* out_val  = (float*)d_out + 67108864;

  prep_k<<<4208, 256, 0, stream>>>(hs, hid_bf, wqa, wqa_bf, wkva, wkva_bf,
                                   mask, flags, wpad_bf);
  mega1_k<<<40512, 256, 0, stream>>>(hid_bf, wqa_bf, part,
                                     wqb, wqb_bf, wkvb, wkvb_bf,
                                     pk, out_key, kb_bf,
                                     pv, out_val, vt_bf);
  post_a_k<<<3072, 256, 0, stream>>>(part, gqa, gkva, qan_bf, ckvn_bf, out_key, kb_bf);
  gemm_bt2<<<3584, 256, 0, stream>>>(qan_bf, wqb_bf, ckvn_bf, wkvb_bf,
                                     q_bf, out_key, out_val, kb_bf, vt_bf);
  attn_k<<<1024, 256, 0, stream>>>(q_bf, kb_bf, vt_bf, mask, flags, out_attn);
}